// Round 2
// baseline (862.797 us; speedup 1.0000x reference)
//
#include <hip/hip_runtime.h>
#include <hip/hip_bf16.h>

typedef __hip_bfloat16 bf16;

#define DEV __device__ __forceinline__

DEV float us2f(unsigned short u){ return __uint_as_float(((unsigned int)u) << 16); }
DEV unsigned short f2us(float f){
    __hip_bfloat16 h = __float2bfloat16(f);
    unsigned short r; __builtin_memcpy(&r, &h, 2); return r;
}

// dtype-flexible loads: F32=true -> input tensor is float32; else bf16
template<bool F32> DEV float ldf(const void* p, long i){
    if (F32) return reinterpret_cast<const float*>(p)[i];
    return us2f(reinterpret_cast<const unsigned short*>(p)[i]);
}
template<bool F32> DEV unsigned short ld16(const void* p, long i){
    if (F32) return f2us(reinterpret_cast<const float*>(p)[i]);
    return reinterpret_cast<const unsigned short*>(p)[i];
}

DEV float wsum(float s){
    s += __shfl_down(s, 32);
    s += __shfl_down(s, 16);
    s += __shfl_down(s, 8);
    s += __shfl_down(s, 4);
    s += __shfl_down(s, 2);
    s += __shfl_down(s, 1);
    return s;
}

// ---------------------------------------------------------------------------
// Kernel 0: dtype detection. mask_V[0] == 1.0 always.
//   bf16: shorts = {0x3F80, ...};  fp32 LE: shorts = {0x0000, 0x3F80}
// ---------------------------------------------------------------------------
__global__ void detect_k(const unsigned short* __restrict__ mv, int* __restrict__ flag){
    if (threadIdx.x == 0 && blockIdx.x == 0)
        *flag = (mv[0] == 0x3F80) ? 0 : 1;
}

// ---------------------------------------------------------------------------
// Kernel A: per-node frames + local/global points + pl_norm -> fp32 workspace
// ---------------------------------------------------------------------------
struct PrepSmem { float sX[9], sR[9], st[3], spl[24]; };

template<bool F32>
DEV void prep_body(const void* hV, const void* X, const void* Wp, const void* bp,
                   float* pg, float* pl, float* pln, float* Rw, float* tw,
                   PrepSmem& s, int n, int tid)
{
    if (tid < 9) s.sX[tid] = ldf<F32>(X, (long)n*9 + tid);
    __syncthreads();

    if (tid == 0) {
        float Nx=s.sX[0],Ny=s.sX[1],Nz=s.sX[2];
        float Ax=s.sX[3],Ay=s.sX[4],Az=s.sX[5];
        float Cx=s.sX[6],Cy=s.sX[7],Cz=s.sX[8];
        float v1x=Cx-Ax, v1y=Cy-Ay, v1z=Cz-Az;
        float v2x=Nx-Ax, v2y=Ny-Ay, v2z=Nz-Az;
        float r1 = 1.f/sqrtf(v1x*v1x+v1y*v1y+v1z*v1z + 1e-8f);
        float e1x=v1x*r1, e1y=v1y*r1, e1z=v1z*r1;
        float dp = e1x*v2x+e1y*v2y+e1z*v2z;
        float u2x=v2x-e1x*dp, u2y=v2y-e1y*dp, u2z=v2z-e1z*dp;
        float r2 = 1.f/sqrtf(u2x*u2x+u2y*u2y+u2z*u2z + 1e-8f);
        float e2x=u2x*r2, e2y=u2y*r2, e2z=u2z*r2;
        float e3x = e1y*e2z - e1z*e2y;
        float e3y = e1z*e2x - e1x*e2z;
        float e3z = e1x*e2y - e1y*e2x;
        s.sR[0]=e1x; s.sR[1]=e2x; s.sR[2]=e3x;
        s.sR[3]=e1y; s.sR[4]=e2y; s.sR[5]=e3y;
        s.sR[6]=e1z; s.sR[7]=e2z; s.sR[8]=e3z;
        s.st[0]=Ax*0.1f; s.st[1]=Ay*0.1f; s.st[2]=Az*0.1f;   // Xca / PSCALE
    }
    if (tid < 24) {
        float acc = ldf<F32>(bp, tid);
        #pragma unroll 4
        for (int i=0;i<128;i++)
            acc += ldf<F32>(hV, (long)n*128 + i) * ldf<F32>(Wp, i*24 + tid);
        s.spl[tid] = acc;
    }
    __syncthreads();

    if (tid < 24) {
        pl[n*24+tid] = s.spl[tid];
        int p = tid/3, c = tid - p*3;
        float g = s.sR[c*3+0]*s.spl[p*3+0] + s.sR[c*3+1]*s.spl[p*3+1]
                + s.sR[c*3+2]*s.spl[p*3+2] + s.st[c];
        pg[n*24+tid] = g;
    }
    if (tid < 9) Rw[n*9+tid] = s.sR[tid];
    if (tid < 3) tw[n*3+tid] = s.st[tid];
    if (tid < 8) {
        float a=s.spl[tid*3], b=s.spl[tid*3+1], c=s.spl[tid*3+2];
        pln[n*8+tid] = sqrtf(a*a+b*b+c*c + 1e-8f);
    }
}

__global__ __launch_bounds__(64) void prep_k(
    const void* __restrict__ hV, const void* __restrict__ X,
    const void* __restrict__ Wp, const void* __restrict__ bp,
    float* __restrict__ pg, float* __restrict__ pl, float* __restrict__ pln,
    float* __restrict__ Rw, float* __restrict__ tw, const int* __restrict__ flag)
{
    __shared__ PrepSmem s;
    int n = blockIdx.x, tid = threadIdx.x;
    if (*flag) prep_body<true >(hV,X,Wp,bp,pg,pl,pln,Rw,tw,s,n,tid);
    else       prep_body<false>(hV,X,Wp,bp,pg,pl,pln,Rw,tw,s,n,tid);
}

// ---------------------------------------------------------------------------
// 16-wide bf16-broadcast FMA helper: acc[kk] += msgT[i][k0+kk] * w
// ---------------------------------------------------------------------------
DEV void fma16_bf(const uint4* mb, int i, float w, float acc[16]) {
    uint4 A = mb[i*4+0];
    uint4 B = mb[i*4+1];
    acc[0]  += __uint_as_float(A.x<<16)          * w;
    acc[1]  += __uint_as_float(A.x&0xffff0000u)  * w;
    acc[2]  += __uint_as_float(A.y<<16)          * w;
    acc[3]  += __uint_as_float(A.y&0xffff0000u)  * w;
    acc[4]  += __uint_as_float(A.z<<16)          * w;
    acc[5]  += __uint_as_float(A.z&0xffff0000u)  * w;
    acc[6]  += __uint_as_float(A.w<<16)          * w;
    acc[7]  += __uint_as_float(A.w&0xffff0000u)  * w;
    acc[8]  += __uint_as_float(B.x<<16)          * w;
    acc[9]  += __uint_as_float(B.x&0xffff0000u)  * w;
    acc[10] += __uint_as_float(B.y<<16)          * w;
    acc[11] += __uint_as_float(B.y&0xffff0000u)  * w;
    acc[12] += __uint_as_float(B.z<<16)          * w;
    acc[13] += __uint_as_float(B.z&0xffff0000u)  * w;
    acc[14] += __uint_as_float(B.w<<16)          * w;
    acc[15] += __uint_as_float(B.w&0xffff0000u)  * w;
}

// ---------------------------------------------------------------------------
// Kernel B: per-node fused message MLP + mean + LN + dense FFN + LN
// ---------------------------------------------------------------------------
struct __align__(16) MpnnSmem {
    unsigned short msgT[456*32];   // [i][k]
    unsigned short m1T[128*32];
    unsigned short m2T[128*32];
    unsigned short shv[128];
    float sR[9], st3[3], spgS[24], splS[24], splnS[8];
    float smka[32];
    int   sj[32];
    float part[2*128];
    float red[4];
    float x1[128];
    float d1[512];
};

template<bool F32>
DEV void mpnn_body(
    const void* hV, const void* hE, const void* maskV, const void* maskA,
    const void* Wm1, const void* bm1, const void* Wm2, const void* bm2,
    const void* Wm3, const void* bm3, const void* g1, const void* be1,
    const void* Wd1, const void* bd1, const void* Wd2, const void* bd2,
    const void* g2, const void* be2, const int* Eidx,
    const float* pg, const float* pl, const float* pln,
    const float* Rw, const float* tw, void* out,
    MpnnSmem& sm, int n, int tid)
{
    int b = n >> 9;
    int h = tid & 127, grp = tid >> 7;

    // ---- stage 0: small per-node loads
    if (tid < 128) sm.shv[tid] = ld16<F32>(hV, (long)n*128 + tid);
    if (tid < 32)       sm.sj[tid]        = b*512 + Eidx[n*32 + tid];
    else if (tid < 64)  sm.smka[tid-32]   = ldf<F32>(maskA, (long)n*32 + (tid-32));
    else if (tid < 88)  sm.spgS[tid-64]   = pg[n*24 + (tid-64)];
    else if (tid < 112) sm.splS[tid-88]   = pl[n*24 + (tid-88)];
    else if (tid < 120) sm.splnS[tid-112] = pln[n*8 + (tid-112)];
    if (tid >= 128 && tid < 137) sm.sR[tid-128]  = Rw[n*9 + (tid-128)];
    if (tid >= 137 && tid < 140) sm.st3[tid-137] = tw[n*3 + (tid-137)];
    __syncthreads();

    // ---- stage 1a: copy segments [h_V | h_E | nbr h_V] into transposed msg
    for (int e = tid; e < 32*384; e += 256) {
        int k = e / 384;
        int i = e - k*384;
        unsigned short v;
        if (i < 128)      v = sm.shv[i];
        else if (i < 256) v = ld16<F32>(hE, ((long)n*32 + k)*128 + (i-128));
        else              v = ld16<F32>(hV, (long)sm.sj[k]*128 + (i-256));
        sm.msgT[i*32 + k] = v;
    }
    // ---- stage 1b: geometric features (one thread per (k,p))
    {
        int k = tid >> 3, p = tid & 7;
        int j = sm.sj[k];
        float qx = pg[j*24 + p*3 + 0];
        float qy = pg[j*24 + p*3 + 1];
        float qz = pg[j*24 + p*3 + 2];
        float dx = sm.spgS[p*3+0]-qx, dy = sm.spgS[p*3+1]-qy, dz = sm.spgS[p*3+2]-qz;
        float npg = sqrtf(dx*dx+dy*dy+dz*dz + 1e-8f);
        float ux = qx - sm.st3[0], uy = qy - sm.st3[1], uz = qz - sm.st3[2];
        float l0 = sm.sR[0]*ux + sm.sR[3]*uy + sm.sR[6]*uz;   // R^T u
        float l1 = sm.sR[1]*ux + sm.sR[4]*uy + sm.sR[7]*uz;
        float l2 = sm.sR[2]*ux + sm.sR[5]*uy + sm.sR[8]*uz;
        float npl = sqrtf(l0*l0+l1*l1+l2*l2 + 1e-8f);
        sm.msgT[(384+p*3+0)*32+k] = f2us(sm.splS[p*3+0]);
        sm.msgT[(384+p*3+1)*32+k] = f2us(sm.splS[p*3+1]);
        sm.msgT[(384+p*3+2)*32+k] = f2us(sm.splS[p*3+2]);
        sm.msgT[(408+p)*32+k]     = f2us(sm.splnS[p]);
        sm.msgT[(416+p*3+0)*32+k] = f2us(l0);
        sm.msgT[(416+p*3+1)*32+k] = f2us(l1);
        sm.msgT[(416+p*3+2)*32+k] = f2us(l2);
        sm.msgT[(440+p)*32+k]     = f2us(npl);
        sm.msgT[(448+p)*32+k]     = f2us(npg);
    }
    __syncthreads();

    const uint4* mbase = reinterpret_cast<const uint4*>(sm.msgT) + (grp<<1);
    const uint4* m1b   = reinterpret_cast<const uint4*>(sm.m1T)  + (grp<<1);
    const uint4* m2b   = reinterpret_cast<const uint4*>(sm.m2T)  + (grp<<1);

    float acc[16];

    // ---- layer 1: 456 -> 128, relu
    {
        float bb = ldf<F32>(bm1, h);
        #pragma unroll
        for (int kk=0;kk<16;kk++) acc[kk]=bb;
        for (int i=0;i<456;i++){
            float w = ldf<F32>(Wm1, (long)i*128 + h);
            fma16_bf(mbase, i, w, acc);
        }
        #pragma unroll
        for (int kk=0;kk<16;kk+=2){
            unsigned pr = (unsigned)f2us(fmaxf(acc[kk],0.f)) | ((unsigned)f2us(fmaxf(acc[kk+1],0.f))<<16);
            reinterpret_cast<unsigned*>(sm.m1T)[h*16 + grp*8 + (kk>>1)] = pr;
        }
    }
    __syncthreads();

    // ---- layer 2: 128 -> 128, relu
    {
        float bb = ldf<F32>(bm2, h);
        #pragma unroll
        for (int kk=0;kk<16;kk++) acc[kk]=bb;
        for (int i=0;i<128;i++){
            float w = ldf<F32>(Wm2, (long)i*128 + h);
            fma16_bf(m1b, i, w, acc);
        }
        #pragma unroll
        for (int kk=0;kk<16;kk+=2){
            unsigned pr = (unsigned)f2us(fmaxf(acc[kk],0.f)) | ((unsigned)f2us(fmaxf(acc[kk+1],0.f))<<16);
            reinterpret_cast<unsigned*>(sm.m2T)[h*16 + grp*8 + (kk>>1)] = pr;
        }
    }
    __syncthreads();

    // ---- layer 3: 128 -> 128, * mask_attend, partial mean over k
    {
        float bb = ldf<F32>(bm3, h);
        #pragma unroll
        for (int kk=0;kk<16;kk++) acc[kk]=bb;
        for (int i=0;i<128;i++){
            float w = ldf<F32>(Wm3, (long)i*128 + h);
            fma16_bf(m2b, i, w, acc);
        }
        float s = 0.f;
        #pragma unroll
        for (int kk=0;kk<16;kk++) s += acc[kk] * sm.smka[grp*16+kk];
        sm.part[grp*128+h] = s;
    }
    __syncthreads();

    if (tid < 128) {
        float nm = (sm.part[tid] + sm.part[128+tid]) * (1.f/32.f);
        sm.x1[tid] = us2f(sm.shv[tid]) + nm;
    }
    __syncthreads();

    // ---- LayerNorm 1
    if (tid < 128) {
        float s = wsum(sm.x1[tid]);
        if ((tid&63)==0) sm.red[tid>>6] = s;
    }
    __syncthreads();
    {
        float mu = (sm.red[0]+sm.red[1]) * (1.f/128.f);
        if (tid < 128) {
            float dv = sm.x1[tid]-mu;
            float s = wsum(dv*dv);
            if ((tid&63)==0) sm.red[2+(tid>>6)] = s;
        }
        __syncthreads();
        if (tid < 128) {
            float var = (sm.red[2]+sm.red[3]) * (1.f/128.f);
            float hv2 = (sm.x1[tid]-mu) * (1.f/sqrtf(var+1e-5f)) * ldf<F32>(g1, h) + ldf<F32>(be1, h);
            sm.x1[tid] = hv2;
        }
    }
    __syncthreads();

    // ---- dense layer 1: 128 -> 512, relu (each thread: 2 outputs)
    {
        float aA = ldf<F32>(bd1, tid), aB = ldf<F32>(bd1, tid+256);
        for (int i=0;i<128;i++){
            float xv = sm.x1[i];
            aA += xv * ldf<F32>(Wd1, (long)i*512 + tid);
            aB += xv * ldf<F32>(Wd1, (long)i*512 + tid + 256);
        }
        sm.d1[tid] = fmaxf(aA, 0.f);
        sm.d1[tid+256] = fmaxf(aB, 0.f);
    }
    __syncthreads();

    // ---- dense layer 2: 512 -> 128 (split over halves)
    {
        float a = grp ? 0.f : ldf<F32>(bd2, h);
        for (int i=0;i<256;i++){
            a += sm.d1[grp*256+i] * ldf<F32>(Wd2, (long)(grp*256+i)*128 + h);
        }
        sm.part[grp*128+h] = a;
    }
    __syncthreads();

    if (tid < 128) sm.x1[tid] = sm.x1[tid] + sm.part[tid] + sm.part[128+tid];
    __syncthreads();

    // ---- LayerNorm 2 + mask_V + store
    if (tid < 128) {
        float s = wsum(sm.x1[tid]);
        if ((tid&63)==0) sm.red[tid>>6] = s;
    }
    __syncthreads();
    {
        float mu = (sm.red[0]+sm.red[1]) * (1.f/128.f);
        if (tid < 128) {
            float dv = sm.x1[tid]-mu;
            float s = wsum(dv*dv);
            if ((tid&63)==0) sm.red[2+(tid>>6)] = s;
        }
        __syncthreads();
        if (tid < 128) {
            float var = (sm.red[2]+sm.red[3]) * (1.f/128.f);
            float v = (sm.x1[tid]-mu) * (1.f/sqrtf(var+1e-5f)) * ldf<F32>(g2, h) + ldf<F32>(be2, h);
            v *= ldf<F32>(maskV, n);
            if (F32) reinterpret_cast<float*>(out)[(long)n*128 + tid] = v;
            else     reinterpret_cast<unsigned short*>(out)[(long)n*128 + tid] = f2us(v);
        }
    }
}

__global__ __launch_bounds__(256) void mpnn_k(
    const void* __restrict__ hV, const void* __restrict__ hE,
    const void* __restrict__ maskV, const void* __restrict__ maskA,
    const void* __restrict__ Wm1, const void* __restrict__ bm1,
    const void* __restrict__ Wm2, const void* __restrict__ bm2,
    const void* __restrict__ Wm3, const void* __restrict__ bm3,
    const void* __restrict__ g1, const void* __restrict__ be1,
    const void* __restrict__ Wd1, const void* __restrict__ bd1,
    const void* __restrict__ Wd2, const void* __restrict__ bd2,
    const void* __restrict__ g2, const void* __restrict__ be2,
    const int* __restrict__ Eidx,
    const float* __restrict__ pg, const float* __restrict__ pl,
    const float* __restrict__ pln, const float* __restrict__ Rw,
    const float* __restrict__ tw, void* __restrict__ out,
    const int* __restrict__ flag)
{
    __shared__ MpnnSmem sm;
    int n = blockIdx.x, tid = threadIdx.x;
    if (*flag)
        mpnn_body<true >(hV,hE,maskV,maskA,Wm1,bm1,Wm2,bm2,Wm3,bm3,g1,be1,
                         Wd1,bd1,Wd2,bd2,g2,be2,Eidx,pg,pl,pln,Rw,tw,out,sm,n,tid);
    else
        mpnn_body<false>(hV,hE,maskV,maskA,Wm1,bm1,Wm2,bm2,Wm3,bm3,g1,be1,
                         Wd1,bd1,Wd2,bd2,g2,be2,Eidx,pg,pl,pln,Rw,tw,out,sm,n,tid);
}

// ---------------------------------------------------------------------------
// Kernel C: h_E passthrough copy (output 1), element width per flag
// ---------------------------------------------------------------------------
__global__ __launch_bounds__(256) void copy_k(const uint4* __restrict__ src,
                                              void* __restrict__ dout,
                                              const int* __restrict__ flag)
{
    bool f32 = (*flag != 0);
    long i = (long)blockIdx.x*256 + threadIdx.x;
    long n16 = f32 ? 4194304L : 2097152L;                 // 67MB vs 33.5MB in uint4s
    uint4* dst = reinterpret_cast<uint4*>(
        reinterpret_cast<char*>(dout) + (f32 ? 524288L*4 : 524288L*2));
    if (i < n16) dst[i] = src[i];
}

// ---------------------------------------------------------------------------
extern "C" void kernel_launch(void* const* d_in, const int* in_sizes, int n_in,
                              void* d_out, int out_size, void* d_ws, size_t ws_size,
                              hipStream_t stream)
{
    const void* hV    = d_in[0];
    const void* hE    = d_in[1];
    const void* X     = d_in[2];
    const void* maskV = d_in[3];
    const void* maskA = d_in[4];
    const void* Wp    = d_in[5];
    const void* bp    = d_in[6];
    const void* Wm1   = d_in[7];
    const void* bm1   = d_in[8];
    const void* Wm2   = d_in[9];
    const void* bm2   = d_in[10];
    const void* Wm3   = d_in[11];
    const void* bm3   = d_in[12];
    const void* g1    = d_in[13];
    const void* be1   = d_in[14];
    const void* Wd1   = d_in[15];
    const void* bd1   = d_in[16];
    const void* Wd2   = d_in[17];
    const void* bd2   = d_in[18];
    const void* g2    = d_in[19];
    const void* be2   = d_in[20];
    const int*  Eidx  = (const int*)d_in[21];

    float* ws   = (float*)d_ws;
    int*   flag = (int*)d_ws;          // ws[0]
    float* pg   = ws + 16;             // 4096*24
    float* pl   = ws + 16 + 98304;
    float* pln  = ws + 16 + 196608;    // 4096*8
    float* Rw   = ws + 16 + 229376;    // 4096*9
    float* tw   = ws + 16 + 266240;    // 4096*3

    detect_k<<<1, 64, 0, stream>>>((const unsigned short*)maskV, flag);

    prep_k<<<4096, 64, 0, stream>>>(hV, X, Wp, bp, pg, pl, pln, Rw, tw, flag);

    mpnn_k<<<4096, 256, 0, stream>>>(hV, hE, maskV, maskA,
                                     Wm1, bm1, Wm2, bm2, Wm3, bm3, g1, be1,
                                     Wd1, bd1, Wd2, bd2, g2, be2, Eidx,
                                     pg, pl, pln, Rw, tw, d_out, flag);

    copy_k<<<16384, 256, 0, stream>>>((const uint4*)hE, d_out, flag);
}

// Round 3
// 333.523 us; speedup vs baseline: 2.5869x; 2.5869x over previous
//
#include <hip/hip_runtime.h>
#include <hip/hip_bf16.h>

typedef __hip_bfloat16 bf16;
typedef __attribute__((ext_vector_type(8))) short s16x8;
typedef __attribute__((ext_vector_type(4))) float f32x4;

#define DEV __device__ __forceinline__

DEV float us2f(unsigned short u){ return __uint_as_float(((unsigned int)u) << 16); }
DEV unsigned short f2us(float f){
    __hip_bfloat16 h = __float2bfloat16(f);
    unsigned short r; __builtin_memcpy(&r, &h, 2); return r;
}
DEV unsigned pack2(float a, float b){ return (unsigned)f2us(a) | ((unsigned)f2us(b) << 16); }

template<bool F32> DEV float ldf(const void* p, long i){
    if (F32) return reinterpret_cast<const float*>(p)[i];
    return us2f(reinterpret_cast<const unsigned short*>(p)[i]);
}
template<bool F32> DEV unsigned short ld16(const void* p, long i){
    if (F32) return f2us(reinterpret_cast<const float*>(p)[i]);
    return reinterpret_cast<const unsigned short*>(p)[i];
}
// load 8 consecutive elems (16B-aligned) as packed bf16 uint4
template<bool F32> DEV uint4 ld8bf(const void* p, long i){
    if (F32) {
        const float4* v = reinterpret_cast<const float4*>(reinterpret_cast<const float*>(p) + i);
        float4 a = v[0], b = v[1];
        uint4 r;
        r.x = pack2(a.x, a.y); r.y = pack2(a.z, a.w);
        r.z = pack2(b.x, b.y); r.w = pack2(b.z, b.w);
        return r;
    }
    return *reinterpret_cast<const uint4*>(reinterpret_cast<const unsigned short*>(p) + i);
}

DEV float wsum(float s){
    s += __shfl_down(s, 32);
    s += __shfl_down(s, 16);
    s += __shfl_down(s, 8);
    s += __shfl_down(s, 4);
    s += __shfl_down(s, 2);
    s += __shfl_down(s, 1);
    return s;
}

// ---------------------------------------------------------------------------
// Kernel 0: dtype detection. mask_V[0] == 1.0 always.
// ---------------------------------------------------------------------------
__global__ void detect_k(const unsigned short* __restrict__ mv, int* __restrict__ flag){
    if (threadIdx.x == 0 && blockIdx.x == 0)
        *flag = (mv[0] == 0x3F80) ? 0 : 1;
}

// ---------------------------------------------------------------------------
// Kernel T: weight pre-transpose to bf16: WT[h][k] = W[k][h]; Wm1 K-padded to 480
// ---------------------------------------------------------------------------
template<bool F32>
DEV void wtrans_body(const void* Wm1, const void* Wm2, const void* Wm3,
                     unsigned short* wt1, unsigned short* wt2, unsigned short* wt3, long t)
{
    if (t < 61440) {                       // 128 x 480
        int h = (int)(t / 480), k = (int)(t % 480);
        wt1[t] = (k < 456) ? ld16<F32>(Wm1, (long)k*128 + h) : (unsigned short)0;
    } else if (t < 61440 + 16384) {        // 128 x 128
        long t2 = t - 61440;
        int h = (int)(t2 >> 7), k = (int)(t2 & 127);
        wt2[t2] = ld16<F32>(Wm2, (long)k*128 + h);
    } else if (t < 61440 + 32768) {
        long t2 = t - 61440 - 16384;
        int h = (int)(t2 >> 7), k = (int)(t2 & 127);
        wt3[t2] = ld16<F32>(Wm3, (long)k*128 + h);
    }
}

__global__ __launch_bounds__(256) void wtrans_k(
    const void* __restrict__ Wm1, const void* __restrict__ Wm2, const void* __restrict__ Wm3,
    unsigned short* __restrict__ wt1, unsigned short* __restrict__ wt2,
    unsigned short* __restrict__ wt3, const int* __restrict__ flag)
{
    long t = (long)blockIdx.x*256 + threadIdx.x;
    if (*flag) wtrans_body<true >(Wm1, Wm2, Wm3, wt1, wt2, wt3, t);
    else       wtrans_body<false>(Wm1, Wm2, Wm3, wt1, wt2, wt3, t);
}

// ---------------------------------------------------------------------------
// Kernel A: per-node frames + local/global points + pl_norm -> fp32 workspace
// ---------------------------------------------------------------------------
struct PrepSmem { float sX[9], sR[9], st[3], spl[24]; };

template<bool F32>
DEV void prep_body(const void* hV, const void* X, const void* Wp, const void* bp,
                   float* pg, float* pl, float* pln, float* Rw, float* tw,
                   PrepSmem& s, int n, int tid)
{
    if (tid < 9) s.sX[tid] = ldf<F32>(X, (long)n*9 + tid);
    __syncthreads();

    if (tid == 0) {
        float Nx=s.sX[0],Ny=s.sX[1],Nz=s.sX[2];
        float Ax=s.sX[3],Ay=s.sX[4],Az=s.sX[5];
        float Cx=s.sX[6],Cy=s.sX[7],Cz=s.sX[8];
        float v1x=Cx-Ax, v1y=Cy-Ay, v1z=Cz-Az;
        float v2x=Nx-Ax, v2y=Ny-Ay, v2z=Nz-Az;
        float r1 = 1.f/sqrtf(v1x*v1x+v1y*v1y+v1z*v1z + 1e-8f);
        float e1x=v1x*r1, e1y=v1y*r1, e1z=v1z*r1;
        float dp = e1x*v2x+e1y*v2y+e1z*v2z;
        float u2x=v2x-e1x*dp, u2y=v2y-e1y*dp, u2z=v2z-e1z*dp;
        float r2 = 1.f/sqrtf(u2x*u2x+u2y*u2y+u2z*u2z + 1e-8f);
        float e2x=u2x*r2, e2y=u2y*r2, e2z=u2z*r2;
        float e3x = e1y*e2z - e1z*e2y;
        float e3y = e1z*e2x - e1x*e2z;
        float e3z = e1x*e2y - e1y*e2x;
        s.sR[0]=e1x; s.sR[1]=e2x; s.sR[2]=e3x;
        s.sR[3]=e1y; s.sR[4]=e2y; s.sR[5]=e3y;
        s.sR[6]=e1z; s.sR[7]=e2z; s.sR[8]=e3z;
        s.st[0]=Ax*0.1f; s.st[1]=Ay*0.1f; s.st[2]=Az*0.1f;
    }
    if (tid < 24) {
        float acc = ldf<F32>(bp, tid);
        #pragma unroll 4
        for (int i=0;i<128;i++)
            acc += ldf<F32>(hV, (long)n*128 + i) * ldf<F32>(Wp, i*24 + tid);
        s.spl[tid] = acc;
    }
    __syncthreads();

    if (tid < 24) {
        pl[n*24+tid] = s.spl[tid];
        int p = tid/3, c = tid - p*3;
        float g = s.sR[c*3+0]*s.spl[p*3+0] + s.sR[c*3+1]*s.spl[p*3+1]
                + s.sR[c*3+2]*s.spl[p*3+2] + s.st[c];
        pg[n*24+tid] = g;
    }
    if (tid < 9) Rw[n*9+tid] = s.sR[tid];
    if (tid < 3) tw[n*3+tid] = s.st[tid];
    if (tid < 8) {
        float a=s.spl[tid*3], b=s.spl[tid*3+1], c=s.spl[tid*3+2];
        pln[n*8+tid] = sqrtf(a*a+b*b+c*c + 1e-8f);
    }
}

__global__ __launch_bounds__(64) void prep_k(
    const void* __restrict__ hV, const void* __restrict__ X,
    const void* __restrict__ Wp, const void* __restrict__ bp,
    float* __restrict__ pg, float* __restrict__ pl, float* __restrict__ pln,
    float* __restrict__ Rw, float* __restrict__ tw, const int* __restrict__ flag)
{
    __shared__ PrepSmem s;
    int n = blockIdx.x, tid = threadIdx.x;
    if (*flag) prep_body<true >(hV,X,Wp,bp,pg,pl,pln,Rw,tw,s,n,tid);
    else       prep_body<false>(hV,X,Wp,bp,pg,pl,pln,Rw,tw,s,n,tid);
}

// ---------------------------------------------------------------------------
// Kernel B: MFMA message-MLP + mean + LN + FFN + LN.  2 nodes / block, 4 waves.
//   wave w: node ln=w>>1, col-half h=w&1. Tiles: 2 (m) x 4 (n) of 16x16x32.
// ---------------------------------------------------------------------------
#define ASTRIDE 40    // bf16 elems per A-chunk row (32 + 8 pad; 80B, 16B-aligned)
#define MSTRIDE 136   // bf16 elems per m1/m2 row (128 + 8 pad; 272B, 16B-aligned)

struct __align__(16) MpnnSmem {
    union __align__(16) {
        unsigned short chunks[4][64*ASTRIDE];   // [0]=dynamic, [1..3]=geo k=384..479
        unsigned short m1[64*MSTRIDE];          // layer-1 output (relu, bf16)
    } r1;
    union __align__(16) {
        unsigned short m2[64*MSTRIDE];          // layer-2 output
        struct { float nodemsg[2][128]; float x1[2][128]; float d1[2][512]; } f;
    } r2;
    int   sj[2][32];
    float smka[2][32];
    float spg[2][24];
    float spl[2][24];
    float spln[2][8];
    float sR[2][9];
    float st3[2][3];
    float red[2][2];
    float red2[2][2];
};

template<bool F32>
DEV void mpnn_body(
    const void* hV, const void* hE, const void* maskV, const void* maskA,
    const void* bm1, const void* bm2, const void* bm3,
    const void* g1, const void* be1,
    const void* Wd1, const void* bd1, const void* Wd2, const void* bd2,
    const void* g2, const void* be2, const int* Eidx,
    const float* pg, const float* pl, const float* pln,
    const float* Rw, const float* tw,
    const unsigned short* wt1, const unsigned short* wt2, const unsigned short* wt3,
    void* out, MpnnSmem& sm, int n0, int tid)
{
    const int lane = tid & 63, w = tid >> 6;
    const int ln = w >> 1, h = w & 1;          // node-in-block, col-half
    const int lm = lane & 15, quad = lane >> 4;

    // ---- stage 0: per-node scalars into LDS
    if (tid < 64)        { int l2=tid>>5, ke=tid&31; int n=n0+l2;
                           sm.sj[l2][ke] = (n>>9)*512 + Eidx[(long)n*32+ke]; }
    else if (tid < 128)  { int t=tid-64;  int l2=t>>5, ke=t&31;
                           sm.smka[l2][ke] = ldf<F32>(maskA, (long)(n0+l2)*32+ke); }
    else if (tid < 176)  { int t=tid-128; int l2=t/24, c=t%24; sm.spg[l2][c] = pg[(n0+l2)*24+c]; }
    else if (tid < 224)  { int t=tid-176; int l2=t/24, c=t%24; sm.spl[l2][c] = pl[(n0+l2)*24+c]; }
    else if (tid < 240)  { int t=tid-224; int l2=t>>3, c=t&7;  sm.spln[l2][c] = pln[(n0+l2)*8+c]; }
    if (tid < 18)        { int l2=tid/9, c=tid%9; sm.sR[l2][c] = Rw[(n0+l2)*9+c]; }
    if (tid >= 18 && tid < 24) { int t=tid-18; int l2=t/3, c=t%3; sm.st3[l2][c] = tw[(n0+l2)*3+c]; }
    __syncthreads();

    // ---- geo static chunks (k = 384..479 -> chunks[1..3]), 512 tasks (row,p)
    #pragma unroll
    for (int pass=0; pass<2; ++pass) {
        int v = tid + pass*256;
        int row = v >> 3, p = v & 7;
        int l2 = row >> 5, ke = row & 31;
        int j = sm.sj[l2][ke];
        float qx = pg[j*24 + p*3 + 0];
        float qy = pg[j*24 + p*3 + 1];
        float qz = pg[j*24 + p*3 + 2];
        float dx = sm.spg[l2][p*3+0]-qx, dy = sm.spg[l2][p*3+1]-qy, dz = sm.spg[l2][p*3+2]-qz;
        float npg = sqrtf(dx*dx+dy*dy+dz*dz + 1e-8f);
        float ux = qx - sm.st3[l2][0], uy = qy - sm.st3[l2][1], uz = qz - sm.st3[l2][2];
        float l0 = sm.sR[l2][0]*ux + sm.sR[l2][3]*uy + sm.sR[l2][6]*uz;
        float l1 = sm.sR[l2][1]*ux + sm.sR[l2][4]*uy + sm.sR[l2][7]*uz;
        float l2v= sm.sR[l2][2]*ux + sm.sR[l2][5]*uy + sm.sR[l2][8]*uz;
        float npl = sqrtf(l0*l0+l1*l1+l2v*l2v + 1e-8f);
        // g' in 0..95 -> chunk 1+(g'>>5), col g'&31
        unsigned short* C0 = sm.r1.chunks[1];
        unsigned short* C1 = sm.r1.chunks[2];
        unsigned short* C2 = sm.r1.chunks[3];
        C0[row*ASTRIDE + p*3+0] = f2us(sm.spl[l2][p*3+0]);
        C0[row*ASTRIDE + p*3+1] = f2us(sm.spl[l2][p*3+1]);
        C0[row*ASTRIDE + p*3+2] = f2us(sm.spl[l2][p*3+2]);
        C0[row*ASTRIDE + 24+p]  = f2us(sm.spln[l2][p]);
        C1[row*ASTRIDE + p*3+0] = f2us(l0);
        C1[row*ASTRIDE + p*3+1] = f2us(l1);
        C1[row*ASTRIDE + p*3+2] = f2us(l2v);
        C1[row*ASTRIDE + 24+p]  = f2us(npl);
        C2[row*ASTRIDE + p]     = f2us(npg);
    }
    // zero-fill chunk2 cols 8..31 (k = 456..479 pad)
    for (int z = tid; z < 64*24; z += 256) {
        int row = z / 24, col = 8 + (z % 24);
        sm.r1.chunks[3][row*ASTRIDE + col] = 0;
    }

    // ================== layer 1: msg[64 x 480] @ WT1 -> [64 x 128] =========
    f32x4 acc[2][4];
    #pragma unroll
    for (int nt=0; nt<4; ++nt) {
        float b0 = ldf<F32>(bm1, 64*h + nt*16 + lm);
        f32x4 iv = {b0,b0,b0,b0};
        acc[0][nt] = iv; acc[1][nt] = iv;
    }
    for (int c=0; c<15; ++c) {
        if (c < 12) {
            __syncthreads();
            {   // stage dynamic chunk: 256 tasks (row 0..63, q 0..3)
                int row = tid >> 2, q = tid & 3;
                int l2 = row >> 5, ke = row & 31;
                int gk = c*32 + q*8;
                const void* base; long src;
                if (c < 4)      { base = hV; src = (long)(n0+l2)*128 + gk; }
                else if (c < 8) { base = hE; src = ((long)(n0+l2)*32 + ke)*128 + (gk-128); }
                else            { base = hV; src = (long)sm.sj[l2][ke]*128 + (gk-256); }
                uint4 vv = ld8bf<F32>(base, src);
                *reinterpret_cast<uint4*>(&sm.r1.chunks[0][row*ASTRIDE + q*8]) = vv;
            }
            __syncthreads();
        }
        const unsigned short* Ab = (c < 12) ? sm.r1.chunks[0] : sm.r1.chunks[c-11];
        s16x8 a0 = *reinterpret_cast<const s16x8*>(&Ab[(32*ln      + lm)*ASTRIDE + quad*8]);
        s16x8 a1 = *reinterpret_cast<const s16x8*>(&Ab[(32*ln + 16 + lm)*ASTRIDE + quad*8]);
        #pragma unroll
        for (int nt=0; nt<4; ++nt) {
            s16x8 bf = *reinterpret_cast<const s16x8*>(&wt1[(long)(64*h + nt*16 + lm)*480 + c*32 + quad*8]);
            acc[0][nt] = __builtin_amdgcn_mfma_f32_16x16x32_bf16(a0, bf, acc[0][nt], 0,0,0);
            acc[1][nt] = __builtin_amdgcn_mfma_f32_16x16x32_bf16(a1, bf, acc[1][nt], 0,0,0);
        }
    }
    // epilogue -> m1 (relu, bf16); m1 aliases chunk region
    __syncthreads();
    #pragma unroll
    for (int mt=0; mt<2; ++mt)
        #pragma unroll
        for (int nt=0; nt<4; ++nt)
            #pragma unroll
            for (int r=0; r<4; ++r)
                sm.r1.m1[(32*ln + mt*16 + quad*4 + r)*MSTRIDE + 64*h + nt*16 + lm]
                    = f2us(fmaxf(acc[mt][nt][r], 0.f));
    __syncthreads();

    // ================== layer 2: m1 @ WT2, relu ============================
    #pragma unroll
    for (int nt=0; nt<4; ++nt) {
        float b0 = ldf<F32>(bm2, 64*h + nt*16 + lm);
        f32x4 iv = {b0,b0,b0,b0};
        acc[0][nt] = iv; acc[1][nt] = iv;
    }
    #pragma unroll
    for (int c=0; c<4; ++c) {
        s16x8 a0 = *reinterpret_cast<const s16x8*>(&sm.r1.m1[(32*ln      + lm)*MSTRIDE + c*32 + quad*8]);
        s16x8 a1 = *reinterpret_cast<const s16x8*>(&sm.r1.m1[(32*ln + 16 + lm)*MSTRIDE + c*32 + quad*8]);
        #pragma unroll
        for (int nt=0; nt<4; ++nt) {
            s16x8 bf = *reinterpret_cast<const s16x8*>(&wt2[(long)(64*h + nt*16 + lm)*128 + c*32 + quad*8]);
            acc[0][nt] = __builtin_amdgcn_mfma_f32_16x16x32_bf16(a0, bf, acc[0][nt], 0,0,0);
            acc[1][nt] = __builtin_amdgcn_mfma_f32_16x16x32_bf16(a1, bf, acc[1][nt], 0,0,0);
        }
    }
    #pragma unroll
    for (int mt=0; mt<2; ++mt)
        #pragma unroll
        for (int nt=0; nt<4; ++nt)
            #pragma unroll
            for (int r=0; r<4; ++r)
                sm.r2.m2[(32*ln + mt*16 + quad*4 + r)*MSTRIDE + 64*h + nt*16 + lm]
                    = f2us(fmaxf(acc[mt][nt][r], 0.f));
    __syncthreads();

    // ================== layer 3: m2 @ WT3 (no relu) ========================
    #pragma unroll
    for (int nt=0; nt<4; ++nt) {
        float b0 = ldf<F32>(bm3, 64*h + nt*16 + lm);
        f32x4 iv = {b0,b0,b0,b0};
        acc[0][nt] = iv; acc[1][nt] = iv;
    }
    #pragma unroll
    for (int c=0; c<4; ++c) {
        s16x8 a0 = *reinterpret_cast<const s16x8*>(&sm.r2.m2[(32*ln      + lm)*MSTRIDE + c*32 + quad*8]);
        s16x8 a1 = *reinterpret_cast<const s16x8*>(&sm.r2.m2[(32*ln + 16 + lm)*MSTRIDE + c*32 + quad*8]);
        #pragma unroll
        for (int nt=0; nt<4; ++nt) {
            s16x8 bf = *reinterpret_cast<const s16x8*>(&wt3[(long)(64*h + nt*16 + lm)*128 + c*32 + quad*8]);
            acc[0][nt] = __builtin_amdgcn_mfma_f32_16x16x32_bf16(a0, bf, acc[0][nt], 0,0,0);
            acc[1][nt] = __builtin_amdgcn_mfma_f32_16x16x32_bf16(a1, bf, acc[1][nt], 0,0,0);
        }
    }
    __syncthreads();   // all waves done reading m2 before nodemsg (aliased) writes

    // masked mean over the node's 32 edges, in-register
    #pragma unroll
    for (int nt=0; nt<4; ++nt) {
        float s = 0.f;
        #pragma unroll
        for (int mt=0; mt<2; ++mt)
            #pragma unroll
            for (int r=0; r<4; ++r)
                s += acc[mt][nt][r] * sm.smka[ln][mt*16 + quad*4 + r];
        s += __shfl_xor(s, 16);
        s += __shfl_xor(s, 32);
        if (lane < 16) sm.r2.f.nodemsg[ln][64*h + nt*16 + lane] = s;
    }
    __syncthreads();

    // ================== LN1 (2 waves per node, 1 col per lane) =============
    const int col = 64*h + lane;
    const int n   = n0 + ln;
    float x = ldf<F32>(hV, (long)n*128 + col) + sm.r2.f.nodemsg[ln][col] * (1.f/32.f);
    {
        float s = wsum(x);
        if (lane == 0) sm.red[ln][h] = s;
    }
    __syncthreads();
    float mu = (sm.red[ln][0] + sm.red[ln][1]) * (1.f/128.f);
    float dv = x - mu;
    {
        float s = wsum(dv*dv);
        if (lane == 0) sm.red2[ln][h] = s;
    }
    __syncthreads();
    float var = (sm.red2[ln][0] + sm.red2[ln][1]) * (1.f/128.f);
    float h1 = dv * (1.f/sqrtf(var + 1e-5f)) * ldf<F32>(g1, col) + ldf<F32>(be1, col);
    sm.r2.f.x1[ln][col] = h1;
    __syncthreads();

    // ================== dense1: 128 -> 512, relu (4 outs/lane) =============
    {
        int j0 = h*256 + lane*4;
        float a0 = ldf<F32>(bd1, j0+0), a1 = ldf<F32>(bd1, j0+1);
        float a2 = ldf<F32>(bd1, j0+2), a3 = ldf<F32>(bd1, j0+3);
        #pragma unroll 4
        for (int i=0; i<128; ++i) {
            float xv = sm.r2.f.x1[ln][i];
            if (F32) {
                float4 wv = *reinterpret_cast<const float4*>(reinterpret_cast<const float*>(Wd1) + (long)i*512 + j0);
                a0 += xv*wv.x; a1 += xv*wv.y; a2 += xv*wv.z; a3 += xv*wv.w;
            } else {
                ushort4 wv = *reinterpret_cast<const ushort4*>(reinterpret_cast<const unsigned short*>(Wd1) + (long)i*512 + j0);
                a0 += xv*us2f(wv.x); a1 += xv*us2f(wv.y); a2 += xv*us2f(wv.z); a3 += xv*us2f(wv.w);
            }
        }
        float4 rv; rv.x = fmaxf(a0,0.f); rv.y = fmaxf(a1,0.f); rv.z = fmaxf(a2,0.f); rv.w = fmaxf(a3,0.f);
        *reinterpret_cast<float4*>(&sm.r2.f.d1[ln][j0]) = rv;
    }
    __syncthreads();

    // ================== dense2: 512 -> 128 (1 out/lane) ====================
    float a2o = ldf<F32>(bd2, col);
    #pragma unroll 8
    for (int i=0; i<512; ++i)
        a2o += sm.r2.f.d1[ln][i] * ldf<F32>(Wd2, (long)i*128 + col);
    float y = h1 + a2o;

    // ================== LN2 + mask_V + store ===============================
    {
        float s = wsum(y);
        if (lane == 0) sm.red[ln][h] = s;
    }
    __syncthreads();
    mu = (sm.red[ln][0] + sm.red[ln][1]) * (1.f/128.f);
    dv = y - mu;
    {
        float s = wsum(dv*dv);
        if (lane == 0) sm.red2[ln][h] = s;
    }
    __syncthreads();
    var = (sm.red2[ln][0] + sm.red2[ln][1]) * (1.f/128.f);
    float v = dv * (1.f/sqrtf(var + 1e-5f)) * ldf<F32>(g2, col) + ldf<F32>(be2, col);
    v *= ldf<F32>(maskV, n);
    if (F32) reinterpret_cast<float*>(out)[(long)n*128 + col] = v;
    else     reinterpret_cast<unsigned short*>(out)[(long)n*128 + col] = f2us(v);
}

__global__ __launch_bounds__(256) void mpnn_k(
    const void* __restrict__ hV, const void* __restrict__ hE,
    const void* __restrict__ maskV, const void* __restrict__ maskA,
    const void* __restrict__ bm1, const void* __restrict__ bm2, const void* __restrict__ bm3,
    const void* __restrict__ g1, const void* __restrict__ be1,
    const void* __restrict__ Wd1, const void* __restrict__ bd1,
    const void* __restrict__ Wd2, const void* __restrict__ bd2,
    const void* __restrict__ g2, const void* __restrict__ be2,
    const int* __restrict__ Eidx,
    const float* __restrict__ pg, const float* __restrict__ pl,
    const float* __restrict__ pln, const float* __restrict__ Rw,
    const float* __restrict__ tw,
    const unsigned short* __restrict__ wt1, const unsigned short* __restrict__ wt2,
    const unsigned short* __restrict__ wt3,
    void* __restrict__ out, const int* __restrict__ flag)
{
    __shared__ MpnnSmem sm;
    int n0 = blockIdx.x * 2, tid = threadIdx.x;
    if (*flag)
        mpnn_body<true >(hV,hE,maskV,maskA,bm1,bm2,bm3,g1,be1,Wd1,bd1,Wd2,bd2,g2,be2,
                         Eidx,pg,pl,pln,Rw,tw,wt1,wt2,wt3,out,sm,n0,tid);
    else
        mpnn_body<false>(hV,hE,maskV,maskA,bm1,bm2,bm3,g1,be1,Wd1,bd1,Wd2,bd2,g2,be2,
                         Eidx,pg,pl,pln,Rw,tw,wt1,wt2,wt3,out,sm,n0,tid);
}

// ---------------------------------------------------------------------------
// Kernel C: h_E passthrough copy (output 1), element width per flag
// ---------------------------------------------------------------------------
__global__ __launch_bounds__(256) void copy_k(const uint4* __restrict__ src,
                                              void* __restrict__ dout,
                                              const int* __restrict__ flag)
{
    bool f32 = (*flag != 0);
    long i = (long)blockIdx.x*256 + threadIdx.x;
    long n16 = f32 ? 4194304L : 2097152L;
    uint4* dst = reinterpret_cast<uint4*>(
        reinterpret_cast<char*>(dout) + (f32 ? 524288L*4 : 524288L*2));
    if (i < n16) dst[i] = src[i];
}

// ---------------------------------------------------------------------------
extern "C" void kernel_launch(void* const* d_in, const int* in_sizes, int n_in,
                              void* d_out, int out_size, void* d_ws, size_t ws_size,
                              hipStream_t stream)
{
    const void* hV    = d_in[0];
    const void* hE    = d_in[1];
    const void* X     = d_in[2];
    const void* maskV = d_in[3];
    const void* maskA = d_in[4];
    const void* Wp    = d_in[5];
    const void* bp    = d_in[6];
    const void* Wm1   = d_in[7];
    const void* bm1   = d_in[8];
    const void* Wm2   = d_in[9];
    const void* bm2   = d_in[10];
    const void* Wm3   = d_in[11];
    const void* bm3   = d_in[12];
    const void* g1    = d_in[13];
    const void* be1   = d_in[14];
    const void* Wd1   = d_in[15];
    const void* bd1   = d_in[16];
    const void* Wd2   = d_in[17];
    const void* bd2   = d_in[18];
    const void* g2    = d_in[19];
    const void* be2   = d_in[20];
    const int*  Eidx  = (const int*)d_in[21];

    float* ws   = (float*)d_ws;
    int*   flag = (int*)d_ws;              // ws[0..15]
    float* pg   = ws + 16;                 // 4096*24
    float* pl   = ws + 16 + 98304;
    float* pln  = ws + 16 + 196608;        // 4096*8
    float* Rw   = ws + 16 + 229376;        // 4096*9
    float* tw   = ws + 16 + 266240;        // 4096*3
    unsigned short* wt1 = (unsigned short*)(ws + 16 + 278528);   // 128*480
    unsigned short* wt2 = wt1 + 61440;                           // 128*128
    unsigned short* wt3 = wt2 + 16384;                           // 128*128

    detect_k<<<1, 64, 0, stream>>>((const unsigned short*)maskV, flag);

    wtrans_k<<<368, 256, 0, stream>>>(Wm1, Wm2, Wm3, wt1, wt2, wt3, flag);

    prep_k<<<4096, 64, 0, stream>>>(hV, X, Wp, bp, pg, pl, pln, Rw, tw, flag);

    mpnn_k<<<2048, 256, 0, stream>>>(hV, hE, maskV, maskA,
                                     bm1, bm2, bm3, g1, be1,
                                     Wd1, bd1, Wd2, bd2, g2, be2, Eidx,
                                     pg, pl, pln, Rw, tw, wt1, wt2, wt3,
                                     d_out, flag);

    copy_k<<<16384, 256, 0, stream>>>((const uint4*)hE, d_out, flag);
}

// Round 4
// 306.652 us; speedup vs baseline: 2.8136x; 1.0876x over previous
//
#include <hip/hip_runtime.h>
#include <hip/hip_bf16.h>

typedef __hip_bfloat16 bf16;
typedef __attribute__((ext_vector_type(8))) short s16x8;
typedef __attribute__((ext_vector_type(4))) float f32x4;

#define DEV __device__ __forceinline__

DEV float us2f(unsigned short u){ return __uint_as_float(((unsigned int)u) << 16); }
DEV unsigned short f2us(float f){
    __hip_bfloat16 h = __float2bfloat16(f);
    unsigned short r; __builtin_memcpy(&r, &h, 2); return r;
}
DEV unsigned pack2(float a, float b){ return (unsigned)f2us(a) | ((unsigned)f2us(b) << 16); }

template<bool F32> DEV float ldf(const void* p, long i){
    if (F32) return reinterpret_cast<const float*>(p)[i];
    return us2f(reinterpret_cast<const unsigned short*>(p)[i]);
}
template<bool F32> DEV unsigned short ld16(const void* p, long i){
    if (F32) return f2us(reinterpret_cast<const float*>(p)[i]);
    return reinterpret_cast<const unsigned short*>(p)[i];
}

// dtype flag read inline by every kernel: maskV[0]==1.0 always.
// bf16 -> first ushort = 0x3F80; fp32 LE -> first ushort = 0x0000.
DEV bool is_f32(const void* maskV){
    return reinterpret_cast<const unsigned short*>(maskV)[0] != 0x3F80;
}

// ---------------------------------------------------------------------------
// Kernel T: weight pre-transposes to bf16 in workspace.
//  wt1[h][k]  = Wm1[k][h]   (128 x 480, K zero-padded 456->480)
//  wt2/wt3    = 128 x 128
//  wpT[j][i]  = Wp[i][j]    (24 x 128)
//  wd1T[n][k] = Wd1[k][n]   (512 x 128)
//  wd2T[n][k] = Wd2[k][n]   (128 x 512)
// ---------------------------------------------------------------------------
template<bool F32>
DEV void wtrans_body(const void* Wm1, const void* Wm2, const void* Wm3,
                     const void* Wp, const void* Wd1, const void* Wd2,
                     unsigned short* wt1, unsigned short* wt2, unsigned short* wt3,
                     unsigned short* wpT, unsigned short* wd1T, unsigned short* wd2T,
                     long t)
{
    if (t < 61440) {
        int h = (int)(t / 480), k = (int)(t % 480);
        wt1[t] = (k < 456) ? ld16<F32>(Wm1, (long)k*128 + h) : (unsigned short)0;
    } else if (t < 77824) {
        long t2 = t - 61440; int h = (int)(t2 >> 7), k = (int)(t2 & 127);
        wt2[t2] = ld16<F32>(Wm2, (long)k*128 + h);
    } else if (t < 94208) {
        long t2 = t - 77824; int h = (int)(t2 >> 7), k = (int)(t2 & 127);
        wt3[t2] = ld16<F32>(Wm3, (long)k*128 + h);
    } else if (t < 97280) {
        long t2 = t - 94208; int j = (int)(t2 >> 7), i = (int)(t2 & 127);
        wpT[t2] = ld16<F32>(Wp, (long)i*24 + j);
    } else if (t < 162816) {
        long t2 = t - 97280; int n = (int)(t2 >> 7), k = (int)(t2 & 127);
        wd1T[t2] = ld16<F32>(Wd1, (long)k*512 + n);
    } else if (t < 228352) {
        long t2 = t - 162816; int n = (int)(t2 >> 9), k = (int)(t2 & 511);
        wd2T[t2] = ld16<F32>(Wd2, (long)k*128 + n);
    }
}

__global__ __launch_bounds__(256) void wtrans_k(
    const void* __restrict__ Wm1, const void* __restrict__ Wm2, const void* __restrict__ Wm3,
    const void* __restrict__ Wp, const void* __restrict__ Wd1, const void* __restrict__ Wd2,
    unsigned short* __restrict__ wt1, unsigned short* __restrict__ wt2,
    unsigned short* __restrict__ wt3, unsigned short* __restrict__ wpT,
    unsigned short* __restrict__ wd1T, unsigned short* __restrict__ wd2T,
    const void* __restrict__ maskV)
{
    long t = (long)blockIdx.x*256 + threadIdx.x;
    if (is_f32(maskV)) wtrans_body<true >(Wm1,Wm2,Wm3,Wp,Wd1,Wd2,wt1,wt2,wt3,wpT,wd1T,wd2T,t);
    else               wtrans_body<false>(Wm1,Wm2,Wm3,Wp,Wd1,Wd2,wt1,wt2,wt3,wpT,wd1T,wd2T,t);
}

// ---------------------------------------------------------------------------
// Kernel A: per-node frames + local/global points + pl_norm -> fp32 workspace
// ---------------------------------------------------------------------------
struct PrepSmem { float sX[9], sR[9], st[3], spl[24], hvs[128]; };

template<bool F32>
DEV void prep_body(const void* hV, const void* X, const unsigned short* wpT, const void* bp,
                   float* pg, float* pl, float* pln, float* Rw, float* tw,
                   PrepSmem& s, int n, int tid)
{
    if (tid < 9) s.sX[tid] = ldf<F32>(X, (long)n*9 + tid);
    for (int i = tid; i < 128; i += 64) s.hvs[i] = ldf<F32>(hV, (long)n*128 + i);
    __syncthreads();

    if (tid == 0) {
        float Nx=s.sX[0],Ny=s.sX[1],Nz=s.sX[2];
        float Ax=s.sX[3],Ay=s.sX[4],Az=s.sX[5];
        float Cx=s.sX[6],Cy=s.sX[7],Cz=s.sX[8];
        float v1x=Cx-Ax, v1y=Cy-Ay, v1z=Cz-Az;
        float v2x=Nx-Ax, v2y=Ny-Ay, v2z=Nz-Az;
        float r1 = 1.f/sqrtf(v1x*v1x+v1y*v1y+v1z*v1z + 1e-8f);
        float e1x=v1x*r1, e1y=v1y*r1, e1z=v1z*r1;
        float dp = e1x*v2x+e1y*v2y+e1z*v2z;
        float u2x=v2x-e1x*dp, u2y=v2y-e1y*dp, u2z=v2z-e1z*dp;
        float r2 = 1.f/sqrtf(u2x*u2x+u2y*u2y+u2z*u2z + 1e-8f);
        float e2x=u2x*r2, e2y=u2y*r2, e2z=u2z*r2;
        float e3x = e1y*e2z - e1z*e2y;
        float e3y = e1z*e2x - e1x*e2z;
        float e3z = e1x*e2y - e1y*e2x;
        s.sR[0]=e1x; s.sR[1]=e2x; s.sR[2]=e3x;
        s.sR[3]=e1y; s.sR[4]=e2y; s.sR[5]=e3y;
        s.sR[6]=e1z; s.sR[7]=e2z; s.sR[8]=e3z;
        s.st[0]=Ax*0.1f; s.st[1]=Ay*0.1f; s.st[2]=Az*0.1f;
    }
    if (tid < 24) {
        float acc = ldf<F32>(bp, tid);
        const unsigned short* wr = wpT + (long)tid*128;
        #pragma unroll
        for (int c=0;c<16;c++){
            ushort4 w0 = *reinterpret_cast<const ushort4*>(wr + c*8);
            ushort4 w1 = *reinterpret_cast<const ushort4*>(wr + c*8 + 4);
            acc += s.hvs[c*8+0]*us2f(w0.x) + s.hvs[c*8+1]*us2f(w0.y)
                 + s.hvs[c*8+2]*us2f(w0.z) + s.hvs[c*8+3]*us2f(w0.w)
                 + s.hvs[c*8+4]*us2f(w1.x) + s.hvs[c*8+5]*us2f(w1.y)
                 + s.hvs[c*8+6]*us2f(w1.z) + s.hvs[c*8+7]*us2f(w1.w);
        }
        s.spl[tid] = acc;
    }
    __syncthreads();

    if (tid < 24) {
        pl[n*24+tid] = s.spl[tid];
        int p = tid/3, c = tid - p*3;
        float g = s.sR[c*3+0]*s.spl[p*3+0] + s.sR[c*3+1]*s.spl[p*3+1]
                + s.sR[c*3+2]*s.spl[p*3+2] + s.st[c];
        pg[n*24+tid] = g;
    }
    if (tid < 9) Rw[n*9+tid] = s.sR[tid];
    if (tid < 3) tw[n*3+tid] = s.st[tid];
    if (tid < 8) {
        float a=s.spl[tid*3], b=s.spl[tid*3+1], c=s.spl[tid*3+2];
        pln[n*8+tid] = sqrtf(a*a+b*b+c*c + 1e-8f);
    }
}

__global__ __launch_bounds__(64) void prep_k(
    const void* __restrict__ hV, const void* __restrict__ X,
    const unsigned short* __restrict__ wpT, const void* __restrict__ bp,
    float* __restrict__ pg, float* __restrict__ pl, float* __restrict__ pln,
    float* __restrict__ Rw, float* __restrict__ tw, const void* __restrict__ maskV)
{
    __shared__ PrepSmem s;
    int n = blockIdx.x, tid = threadIdx.x;
    if (is_f32(maskV)) prep_body<true >(hV,X,wpT,bp,pg,pl,pln,Rw,tw,s,n,tid);
    else               prep_body<false>(hV,X,wpT,bp,pg,pl,pln,Rw,tw,s,n,tid);
}

// ---------------------------------------------------------------------------
// Kernel B1: edge-MLP (3 MFMA layers) + masked mean -> nodemsg (fp32).
//   2 nodes / block, 4 waves. Single-barrier pipelined K-loop.
//   Also writes the h_E passthrough output while staging chunks 4..7.
// ---------------------------------------------------------------------------
#define ASTRIDE 40    // 32 + 8 pad (80B rows, 16B-aligned)
#define MSTRIDE 136   // 128 + 8 pad (272B rows, 16B-aligned)

struct __align__(16) Mp1Smem {
    union __align__(16) {
        unsigned short bufs[2][64*ASTRIDE];   // dynamic chunk double-buffer
        unsigned short m1[64*MSTRIDE];        // layer-1 output
    } u1;
    union __align__(16) {
        unsigned short geo[3][64*ASTRIDE];    // geo k=384..479
        unsigned short m2[64*MSTRIDE];        // layer-2 output
    } u2;
    int   sj[2][32];
    float smka[2][32];
    float spg[2][24], spl[2][24], spln[2][8];
    float sR[2][9], st3[2][3];
};

template<bool F32>
DEV void mpnn1_body(
    const void* hV, const void* hE, const void* maskA,
    const void* bm1, const void* bm2, const void* bm3, const int* Eidx,
    const float* pg, const float* pl, const float* pln,
    const float* Rw, const float* tw,
    const unsigned short* wt1, const unsigned short* wt2, const unsigned short* wt3,
    float* nodemsg, void* outE, Mp1Smem& sm, int n0, int tid)
{
    const int lane = tid & 63, w = tid >> 6;
    const int ln = w >> 1, h = w & 1;
    const int lm = lane & 15, quad = lane >> 4;

    // ---- stage 0
    if (tid < 64)        { int l2=tid>>5, ke=tid&31; int n=n0+l2;
                           sm.sj[l2][ke] = (n>>9)*512 + Eidx[(long)n*32+ke]; }
    else if (tid < 128)  { int t=tid-64;  int l2=t>>5, ke=t&31;
                           sm.smka[l2][ke] = ldf<F32>(maskA, (long)(n0+l2)*32+ke); }
    else if (tid < 176)  { int t=tid-128; int l2=t/24, c=t%24; sm.spg[l2][c] = pg[(n0+l2)*24+c]; }
    else if (tid < 224)  { int t=tid-176; int l2=t/24, c=t%24; sm.spl[l2][c] = pl[(n0+l2)*24+c]; }
    else if (tid < 240)  { int t=tid-224; int l2=t>>3, c=t&7;  sm.spln[l2][c] = pln[(n0+l2)*8+c]; }
    if (tid < 18)        { int l2=tid/9, c=tid%9; sm.sR[l2][c] = Rw[(n0+l2)*9+c]; }
    if (tid >= 18 && tid < 24) { int t=tid-18; int l2=t/3, c=t%3; sm.st3[l2][c] = tw[(n0+l2)*3+c]; }
    __syncthreads();

    // ---- geo chunks (k=384..479), 512 (row,p) tasks
    #pragma unroll
    for (int pass=0; pass<2; ++pass) {
        int v = tid + pass*256;
        int row = v >> 3, p = v & 7;
        int l2 = row >> 5;
        int j = sm.sj[l2][row & 31];
        float qx = pg[j*24 + p*3 + 0];
        float qy = pg[j*24 + p*3 + 1];
        float qz = pg[j*24 + p*3 + 2];
        float dx = sm.spg[l2][p*3+0]-qx, dy = sm.spg[l2][p*3+1]-qy, dz = sm.spg[l2][p*3+2]-qz;
        float npg = sqrtf(dx*dx+dy*dy+dz*dz + 1e-8f);
        float ux = qx - sm.st3[l2][0], uy = qy - sm.st3[l2][1], uz = qz - sm.st3[l2][2];
        float l0 = sm.sR[l2][0]*ux + sm.sR[l2][3]*uy + sm.sR[l2][6]*uz;
        float l1 = sm.sR[l2][1]*ux + sm.sR[l2][4]*uy + sm.sR[l2][7]*uz;
        float l2v= sm.sR[l2][2]*ux + sm.sR[l2][5]*uy + sm.sR[l2][8]*uz;
        float npl = sqrtf(l0*l0+l1*l1+l2v*l2v + 1e-8f);
        unsigned short* C0 = sm.u2.geo[0];
        unsigned short* C1 = sm.u2.geo[1];
        unsigned short* C2 = sm.u2.geo[2];
        C0[row*ASTRIDE + p*3+0] = f2us(sm.spl[l2][p*3+0]);
        C0[row*ASTRIDE + p*3+1] = f2us(sm.spl[l2][p*3+1]);
        C0[row*ASTRIDE + p*3+2] = f2us(sm.spl[l2][p*3+2]);
        C0[row*ASTRIDE + 24+p]  = f2us(sm.spln[l2][p]);
        C1[row*ASTRIDE + p*3+0] = f2us(l0);
        C1[row*ASTRIDE + p*3+1] = f2us(l1);
        C1[row*ASTRIDE + p*3+2] = f2us(l2v);
        C1[row*ASTRIDE + 24+p]  = f2us(npl);
        C2[row*ASTRIDE + p]     = f2us(npg);
    }
    for (int z = tid; z < 64*24; z += 256) {
        int row = z / 24, col = 8 + (z % 24);
        sm.u2.geo[2][row*ASTRIDE + col] = 0;
    }

    // ---- pipelined K-loop, layer 1 (K = 480 = 15 chunks of 32; 12 dynamic)
    const int srow = tid >> 2, q = tid & 3;
    const int sl2 = srow >> 5, ske = srow & 31;
    float4 stA, stB; uint4 stP;

    auto loadchunk = [&](int c){
        int gk = c*32 + q*8;
        const void* base; long src;
        if (c < 4)      { base = hV; src = (long)(n0+sl2)*128 + gk; }
        else if (c < 8) { base = hE; src = ((long)(n0+sl2)*32 + ske)*128 + (gk-128); }
        else            { base = hV; src = (long)sm.sj[sl2][ske]*128 + (gk-256); }
        if (F32) {
            const float4* vp = reinterpret_cast<const float4*>(reinterpret_cast<const float*>(base) + src);
            stA = vp[0]; stB = vp[1];
        } else {
            stP = *reinterpret_cast<const uint4*>(reinterpret_cast<const unsigned short*>(base) + src);
        }
    };
    auto commit = [&](int c){
        uint4 v;
        if (F32) { v.x=pack2(stA.x,stA.y); v.y=pack2(stA.z,stA.w);
                   v.z=pack2(stB.x,stB.y); v.w=pack2(stB.z,stB.w); }
        else v = stP;
        *reinterpret_cast<uint4*>(&sm.u1.bufs[c&1][srow*ASTRIDE + q*8]) = v;
        if (c >= 4 && c < 8) {   // fold h_E passthrough output
            long off = ((long)(n0+sl2)*32 + ske)*128 + (c-4)*32 + q*8;
            if (F32) {
                float4* d = reinterpret_cast<float4*>(reinterpret_cast<float*>(outE) + off);
                d[0] = stA; d[1] = stB;
            } else {
                *reinterpret_cast<uint4*>(reinterpret_cast<unsigned short*>(outE) + off) = stP;
            }
        }
    };

    f32x4 acc[2][4];
    #pragma unroll
    for (int nt=0; nt<4; ++nt) {
        float b0 = ldf<F32>(bm1, 64*h + nt*16 + lm);
        f32x4 iv = {b0,b0,b0,b0};
        acc[0][nt] = iv; acc[1][nt] = iv;
    }

    loadchunk(0);
    for (int c=0; c<15; ++c) {
        if (c < 12) {
            commit(c);
            if (c+1 < 12) loadchunk(c+1);    // in flight across the barrier
        }
        __syncthreads();
        const unsigned short* Ab = (c < 12) ? sm.u1.bufs[c&1] : sm.u2.geo[c-12];
        s16x8 a0 = *reinterpret_cast<const s16x8*>(&Ab[(32*ln      + lm)*ASTRIDE + quad*8]);
        s16x8 a1 = *reinterpret_cast<const s16x8*>(&Ab[(32*ln + 16 + lm)*ASTRIDE + quad*8]);
        #pragma unroll
        for (int nt=0; nt<4; ++nt) {
            s16x8 bf = *reinterpret_cast<const s16x8*>(&wt1[(long)(64*h + nt*16 + lm)*480 + c*32 + quad*8]);
            acc[0][nt] = __builtin_amdgcn_mfma_f32_16x16x32_bf16(a0, bf, acc[0][nt], 0,0,0);
            acc[1][nt] = __builtin_amdgcn_mfma_f32_16x16x32_bf16(a1, bf, acc[1][nt], 0,0,0);
        }
    }
    __syncthreads();
    #pragma unroll
    for (int mt=0; mt<2; ++mt)
        #pragma unroll
        for (int nt=0; nt<4; ++nt)
            #pragma unroll
            for (int r=0; r<4; ++r)
                sm.u1.m1[(32*ln + mt*16 + quad*4 + r)*MSTRIDE + 64*h + nt*16 + lm]
                    = f2us(fmaxf(acc[mt][nt][r], 0.f));
    __syncthreads();

    // ---- layer 2
    #pragma unroll
    for (int nt=0; nt<4; ++nt) {
        float b0 = ldf<F32>(bm2, 64*h + nt*16 + lm);
        f32x4 iv = {b0,b0,b0,b0};
        acc[0][nt] = iv; acc[1][nt] = iv;
    }
    #pragma unroll
    for (int c=0; c<4; ++c) {
        s16x8 a0 = *reinterpret_cast<const s16x8*>(&sm.u1.m1[(32*ln      + lm)*MSTRIDE + c*32 + quad*8]);
        s16x8 a1 = *reinterpret_cast<const s16x8*>(&sm.u1.m1[(32*ln + 16 + lm)*MSTRIDE + c*32 + quad*8]);
        #pragma unroll
        for (int nt=0; nt<4; ++nt) {
            s16x8 bf = *reinterpret_cast<const s16x8*>(&wt2[(long)(64*h + nt*16 + lm)*128 + c*32 + quad*8]);
            acc[0][nt] = __builtin_amdgcn_mfma_f32_16x16x32_bf16(a0, bf, acc[0][nt], 0,0,0);
            acc[1][nt] = __builtin_amdgcn_mfma_f32_16x16x32_bf16(a1, bf, acc[1][nt], 0,0,0);
        }
    }
    #pragma unroll
    for (int mt=0; mt<2; ++mt)
        #pragma unroll
        for (int nt=0; nt<4; ++nt)
            #pragma unroll
            for (int r=0; r<4; ++r)
                sm.u2.m2[(32*ln + mt*16 + quad*4 + r)*MSTRIDE + 64*h + nt*16 + lm]
                    = f2us(fmaxf(acc[mt][nt][r], 0.f));
    __syncthreads();

    // ---- layer 3 + masked mean (raw sum; /32 applied in ffn_k)
    #pragma unroll
    for (int nt=0; nt<4; ++nt) {
        float b0 = ldf<F32>(bm3, 64*h + nt*16 + lm);
        f32x4 iv = {b0,b0,b0,b0};
        acc[0][nt] = iv; acc[1][nt] = iv;
    }
    #pragma unroll
    for (int c=0; c<4; ++c) {
        s16x8 a0 = *reinterpret_cast<const s16x8*>(&sm.u2.m2[(32*ln      + lm)*MSTRIDE + c*32 + quad*8]);
        s16x8 a1 = *reinterpret_cast<const s16x8*>(&sm.u2.m2[(32*ln + 16 + lm)*MSTRIDE + c*32 + quad*8]);
        #pragma unroll
        for (int nt=0; nt<4; ++nt) {
            s16x8 bf = *reinterpret_cast<const s16x8*>(&wt3[(long)(64*h + nt*16 + lm)*128 + c*32 + quad*8]);
            acc[0][nt] = __builtin_amdgcn_mfma_f32_16x16x32_bf16(a0, bf, acc[0][nt], 0,0,0);
            acc[1][nt] = __builtin_amdgcn_mfma_f32_16x16x32_bf16(a1, bf, acc[1][nt], 0,0,0);
        }
    }
    #pragma unroll
    for (int nt=0; nt<4; ++nt) {
        float s = 0.f;
        #pragma unroll
        for (int mt=0; mt<2; ++mt)
            #pragma unroll
            for (int r=0; r<4; ++r)
                s += acc[mt][nt][r] * sm.smka[ln][mt*16 + quad*4 + r];
        s += __shfl_xor(s, 16);
        s += __shfl_xor(s, 32);
        if (lane < 16)
            nodemsg[(long)(n0+ln)*128 + 64*h + nt*16 + lane] = s;
    }
}

__global__ __launch_bounds__(256) void mpnn1_k(
    const void* __restrict__ hV, const void* __restrict__ hE,
    const void* __restrict__ maskV, const void* __restrict__ maskA,
    const void* __restrict__ bm1, const void* __restrict__ bm2, const void* __restrict__ bm3,
    const int* __restrict__ Eidx,
    const float* __restrict__ pg, const float* __restrict__ pl,
    const float* __restrict__ pln, const float* __restrict__ Rw,
    const float* __restrict__ tw,
    const unsigned short* __restrict__ wt1, const unsigned short* __restrict__ wt2,
    const unsigned short* __restrict__ wt3,
    float* __restrict__ nodemsg, void* __restrict__ dout)
{
    __shared__ Mp1Smem sm;
    int n0 = blockIdx.x * 2, tid = threadIdx.x;
    if (is_f32(maskV)) {
        void* outE = reinterpret_cast<float*>(dout) + 524288;
        mpnn1_body<true >(hV,hE,maskA,bm1,bm2,bm3,Eidx,pg,pl,pln,Rw,tw,wt1,wt2,wt3,nodemsg,outE,sm,n0,tid);
    } else {
        void* outE = reinterpret_cast<unsigned short*>(dout) + 524288;
        mpnn1_body<false>(hV,hE,maskA,bm1,bm2,bm3,Eidx,pg,pl,pln,Rw,tw,wt1,wt2,wt3,nodemsg,outE,sm,n0,tid);
    }
}

// ---------------------------------------------------------------------------
// Kernel B2: node FFN as batched MFMA GEMM. 64 nodes / block, 64 blocks.
//   LN1 -> x1(bf16) ; for cc: t1 = relu(x1@Wd1[:,cc]) ; y += t1@Wd2[cc,:]
//   -> +res, LN2, mask, store.
// ---------------------------------------------------------------------------
struct __align__(16) FfnSmem {
    unsigned short x1[64*MSTRIDE];          // LN1 output, bf16
    union __align__(16) {
        unsigned short t1[64*MSTRIDE];      // hidden chunk, bf16
        float yf[64*132];                   // pre-LN2 rows, fp32
    } u;
};

template<bool F32>
DEV void ffn_body(const void* hV, const void* maskV, const float* nodemsg,
                  const void* g1, const void* be1, const void* bd1, const void* bd2,
                  const void* g2, const void* be2,
                  const unsigned short* wd1T, const unsigned short* wd2T,
                  void* out, FfnSmem& sm, int n0, int tid)
{
    const int lane = tid & 63, w = tid >> 6;
    const int lm = lane & 15, quad = lane >> 4;

    // ---- x = hV + nodemsg/32 ; LN1 -> x1 (bf16)
    {
        const int r = tid >> 2, qq = tid & 3;
        const long nb = (long)(n0 + r)*128 + qq*32;
        float xv[32];
        float s1 = 0.f, s2 = 0.f;
        #pragma unroll
        for (int j=0; j<32; ++j) {
            float v = ldf<F32>(hV, nb + j) + nodemsg[nb + j] * (1.f/32.f);
            xv[j] = v; s1 += v; s2 += v*v;
        }
        s1 += __shfl_xor(s1, 1); s1 += __shfl_xor(s1, 2);
        s2 += __shfl_xor(s2, 1); s2 += __shfl_xor(s2, 2);
        float mu = s1 * (1.f/128.f);
        float var = s2 * (1.f/128.f) - mu*mu;
        float rs = 1.f/sqrtf(var + 1e-5f);
        #pragma unroll
        for (int j=0; j<32; ++j) {
            int c = qq*32 + j;
            float h1 = (xv[j]-mu)*rs*ldf<F32>(g1, c) + ldf<F32>(be1, c);
            sm.x1[r*MSTRIDE + c] = f2us(h1);
        }
    }
    __syncthreads();

    // ---- GEMM: wave w owns m-tile w (rows 16w..16w+15), all 8 n-tiles
    f32x4 yacc[8];
    #pragma unroll
    for (int nt=0; nt<8; ++nt) {
        float b0 = ldf<F32>(bd2, nt*16 + lm);
        f32x4 iv = {b0,b0,b0,b0};
        yacc[nt] = iv;
    }
    for (int cc=0; cc<4; ++cc) {
        f32x4 t1a[8];
        #pragma unroll
        for (int nt=0; nt<8; ++nt) {
            float b0 = ldf<F32>(bd1, cc*128 + nt*16 + lm);
            f32x4 iv = {b0,b0,b0,b0};
            t1a[nt] = iv;
        }
        #pragma unroll
        for (int kb=0; kb<4; ++kb) {
            s16x8 a = *reinterpret_cast<const s16x8*>(&sm.x1[(16*w + lm)*MSTRIDE + kb*32 + quad*8]);
            #pragma unroll
            for (int nt=0; nt<8; ++nt) {
                s16x8 bf = *reinterpret_cast<const s16x8*>(&wd1T[(long)(cc*128 + nt*16 + lm)*128 + kb*32 + quad*8]);
                t1a[nt] = __builtin_amdgcn_mfma_f32_16x16x32_bf16(a, bf, t1a[nt], 0,0,0);
            }
        }
        __syncthreads();   // prior GEMM2 reads of t1 done
        #pragma unroll
        for (int nt=0; nt<8; ++nt)
            #pragma unroll
            for (int r=0; r<4; ++r)
                sm.u.t1[(16*w + quad*4 + r)*MSTRIDE + nt*16 + lm] = f2us(fmaxf(t1a[nt][r], 0.f));
        __syncthreads();
        #pragma unroll
        for (int kb=0; kb<4; ++kb) {
            s16x8 a = *reinterpret_cast<const s16x8*>(&sm.u.t1[(16*w + lm)*MSTRIDE + kb*32 + quad*8]);
            #pragma unroll
            for (int nt=0; nt<8; ++nt) {
                s16x8 bf = *reinterpret_cast<const s16x8*>(&wd2T[(long)(nt*16 + lm)*512 + cc*128 + kb*32 + quad*8]);
                yacc[nt] = __builtin_amdgcn_mfma_f32_16x16x32_bf16(a, bf, yacc[nt], 0,0,0);
            }
        }
    }
    __syncthreads();   // last GEMM2 reads done before yf (alias t1) writes

    // ---- y = h1 + ffn -> yf
    #pragma unroll
    for (int nt=0; nt<8; ++nt)
        #pragma unroll
        for (int r=0; r<4; ++r) {
            int rr = 16*w + quad*4 + r, c = nt*16 + lm;
            sm.u.yf[rr*132 + c] = yacc[nt][r] + us2f(sm.x1[rr*MSTRIDE + c]);
        }
    __syncthreads();

    // ---- LN2 + mask + store
    {
        const int r = tid >> 2, qq = tid & 3;
        float yv[32];
        float s1 = 0.f, s2 = 0.f;
        #pragma unroll
        for (int j=0; j<32; ++j) {
            float v = sm.u.yf[r*132 + qq*32 + j];
            yv[j] = v; s1 += v; s2 += v*v;
        }
        s1 += __shfl_xor(s1, 1); s1 += __shfl_xor(s1, 2);
        s2 += __shfl_xor(s2, 1); s2 += __shfl_xor(s2, 2);
        float mu = s1 * (1.f/128.f);
        float var = s2 * (1.f/128.f) - mu*mu;
        float rs = 1.f/sqrtf(var + 1e-5f);
        float mv = ldf<F32>(maskV, n0 + r);
        const long ob = (long)(n0 + r)*128 + qq*32;
        #pragma unroll
        for (int j=0; j<32; ++j) {
            int c = qq*32 + j;
            float v = (yv[j]-mu)*rs*ldf<F32>(g2, c) + ldf<F32>(be2, c);
            v *= mv;
            if (F32) reinterpret_cast<float*>(out)[ob + j] = v;
            else     reinterpret_cast<unsigned short*>(out)[ob + j] = f2us(v);
        }
    }
}

__global__ __launch_bounds__(256) void ffn_k(
    const void* __restrict__ hV, const void* __restrict__ maskV,
    const float* __restrict__ nodemsg,
    const void* __restrict__ g1, const void* __restrict__ be1,
    const void* __restrict__ bd1, const void* __restrict__ bd2,
    const void* __restrict__ g2, const void* __restrict__ be2,
    const unsigned short* __restrict__ wd1T, const unsigned short* __restrict__ wd2T,
    void* __restrict__ out)
{
    __shared__ FfnSmem sm;
    int n0 = blockIdx.x * 64, tid = threadIdx.x;
    if (is_f32(maskV))
        ffn_body<true >(hV,maskV,nodemsg,g1,be1,bd1,bd2,g2,be2,wd1T,wd2T,out,sm,n0,tid);
    else
        ffn_body<false>(hV,maskV,nodemsg,g1,be1,bd1,bd2,g2,be2,wd1T,wd2T,out,sm,n0,tid);
}

// ---------------------------------------------------------------------------
extern "C" void kernel_launch(void* const* d_in, const int* in_sizes, int n_in,
                              void* d_out, int out_size, void* d_ws, size_t ws_size,
                              hipStream_t stream)
{
    const void* hV    = d_in[0];
    const void* hE    = d_in[1];
    const void* X     = d_in[2];
    const void* maskV = d_in[3];
    const void* maskA = d_in[4];
    const void* Wp    = d_in[5];
    const void* bp    = d_in[6];
    const void* Wm1   = d_in[7];
    const void* bm1   = d_in[8];
    const void* Wm2   = d_in[9];
    const void* bm2   = d_in[10];
    const void* Wm3   = d_in[11];
    const void* bm3   = d_in[12];
    const void* g1    = d_in[13];
    const void* be1   = d_in[14];
    const void* Wd1   = d_in[15];
    const void* bd1   = d_in[16];
    const void* Wd2   = d_in[17];
    const void* bd2   = d_in[18];
    const void* g2    = d_in[19];
    const void* be2   = d_in[20];
    const int*  Eidx  = (const int*)d_in[21];

    float* ws = (float*)d_ws;
    float* pg  = ws;                 // 4096*24 = 98304
    float* pl  = ws + 98304;         // 98304
    float* pln = ws + 196608;        // 32768
    float* Rw  = ws + 229376;        // 36864
    float* tw  = ws + 266240;        // 12288
    float* nm  = ws + 278528;        // nodemsg: 4096*128 = 524288
    unsigned short* wt1  = (unsigned short*)(ws + 802816);  // 61440
    unsigned short* wt2  = wt1 + 61440;                     // 16384
    unsigned short* wt3  = wt2 + 16384;                     // 16384
    unsigned short* wpT  = wt3 + 16384;                     // 3072
    unsigned short* wd1T = wpT + 3072;                      // 65536
    unsigned short* wd2T = wd1T + 65536;                    // 65536

    wtrans_k<<<892, 256, 0, stream>>>(Wm1, Wm2, Wm3, Wp, Wd1, Wd2,
                                      wt1, wt2, wt3, wpT, wd1T, wd2T, maskV);

    prep_k<<<4096, 64, 0, stream>>>(hV, X, wpT, bp, pg, pl, pln, Rw, tw, maskV);

    mpnn1_k<<<2048, 256, 0, stream>>>(hV, hE, maskV, maskA, bm1, bm2, bm3, Eidx,
                                      pg, pl, pln, Rw, tw, wt1, wt2, wt3,
                                      nm, d_out);

    ffn_k<<<64, 256, 0, stream>>>(hV, maskV, nm, g1, be1, bd1, bd2, g2, be2,
                                  wd1T, wd2T, d_out);
}

// Round 5
// 279.155 us; speedup vs baseline: 3.0908x; 1.0985x over previous
//
#include <hip/hip_runtime.h>
#include <hip/hip_bf16.h>

typedef __hip_bfloat16 bf16;
typedef __attribute__((ext_vector_type(8))) short s16x8;
typedef __attribute__((ext_vector_type(4))) float f32x4;

#define DEV __device__ __forceinline__

DEV float us2f(unsigned short u){ return __uint_as_float(((unsigned int)u) << 16); }
DEV unsigned short f2us(float f){
    __hip_bfloat16 h = __float2bfloat16(f);
    unsigned short r; __builtin_memcpy(&r, &h, 2); return r;
}
DEV unsigned pack2(float a, float b){ return (unsigned)f2us(a) | ((unsigned)f2us(b) << 16); }

template<bool F32> DEV float ldf(const void* p, long i){
    if (F32) return reinterpret_cast<const float*>(p)[i];
    return us2f(reinterpret_cast<const unsigned short*>(p)[i]);
}
template<bool F32> DEV unsigned short ld16(const void* p, long i){
    if (F32) return f2us(reinterpret_cast<const float*>(p)[i]);
    return reinterpret_cast<const unsigned short*>(p)[i];
}

union U16x8 { uint4 u; s16x8 v; };

// dtype flag: maskV[0]==1.0 always. bf16 -> ushort0 = 0x3F80; fp32 LE -> 0x0000.
DEV bool is_f32(const void* maskV){
    return reinterpret_cast<const unsigned short*>(maskV)[0] != 0x3F80;
}

// ---------------------------------------------------------------------------
// Kernel T: weight pre-transposes (coalesced reads, scattered stores).
// ---------------------------------------------------------------------------
template<bool F32>
DEV void wtrans_body(const void* Wm1, const void* Wm2, const void* Wm3,
                     const void* Wp, const void* Wd1, const void* Wd2,
                     unsigned short* wt1, unsigned short* wt2, unsigned short* wt3,
                     unsigned short* wpT, unsigned short* wd1T, unsigned short* wd2T,
                     long t)
{
    if (t < 61440) {                 // wt1[h][k] = Wm1[k][h], K padded to 480
        int k = (int)(t >> 7), h = (int)(t & 127);
        wt1[(long)h*480 + k] = (k < 456) ? ld16<F32>(Wm1, (long)k*128 + h) : (unsigned short)0;
    } else if (t < 77824) {
        long t2 = t - 61440; int k = (int)(t2 >> 7), h = (int)(t2 & 127);
        wt2[(long)h*128 + k] = ld16<F32>(Wm2, (long)k*128 + h);
    } else if (t < 94208) {
        long t2 = t - 77824; int k = (int)(t2 >> 7), h = (int)(t2 & 127);
        wt3[(long)h*128 + k] = ld16<F32>(Wm3, (long)k*128 + h);
    } else if (t < 97280) {
        long t2 = t - 94208; int i = (int)(t2 / 24), j = (int)(t2 % 24);
        wpT[(long)j*128 + i] = ld16<F32>(Wp, (long)i*24 + j);
    } else if (t < 162816) {         // wd1T[n][k] = Wd1[k][n]  (512 x 128)
        long t2 = t - 97280; int k = (int)(t2 >> 9), n = (int)(t2 & 511);
        wd1T[(long)n*128 + k] = ld16<F32>(Wd1, (long)k*512 + n);
    } else if (t < 228352) {         // wd2T[n][k] = Wd2[k][n]  (128 x 512)
        long t2 = t - 162816; int k = (int)(t2 >> 7), n = (int)(t2 & 127);
        wd2T[(long)n*512 + k] = ld16<F32>(Wd2, (long)k*128 + n);
    }
}

__global__ __launch_bounds__(256) void wtrans_k(
    const void* __restrict__ Wm1, const void* __restrict__ Wm2, const void* __restrict__ Wm3,
    const void* __restrict__ Wp, const void* __restrict__ Wd1, const void* __restrict__ Wd2,
    unsigned short* __restrict__ wt1, unsigned short* __restrict__ wt2,
    unsigned short* __restrict__ wt3, unsigned short* __restrict__ wpT,
    unsigned short* __restrict__ wd1T, unsigned short* __restrict__ wd2T,
    const void* __restrict__ maskV)
{
    long t = (long)blockIdx.x*256 + threadIdx.x;
    if (is_f32(maskV)) wtrans_body<true >(Wm1,Wm2,Wm3,Wp,Wd1,Wd2,wt1,wt2,wt3,wpT,wd1T,wd2T,t);
    else               wtrans_body<false>(Wm1,Wm2,Wm3,Wp,Wd1,Wd2,wt1,wt2,wt3,wpT,wd1T,wd2T,t);
}

// ---------------------------------------------------------------------------
// Kernel A: per-node frames + local/global points + pl_norm -> fp32 workspace
// ---------------------------------------------------------------------------
struct PrepSmem { float sX[9], sR[9], st[3], spl[24], hvs[128]; };

template<bool F32>
DEV void prep_body(const void* hV, const void* X, const unsigned short* wpT, const void* bp,
                   float* pg, float* pl, float* pln, float* Rw, float* tw,
                   PrepSmem& s, int n, int tid)
{
    if (tid < 9) s.sX[tid] = ldf<F32>(X, (long)n*9 + tid);
    for (int i = tid; i < 128; i += 64) s.hvs[i] = ldf<F32>(hV, (long)n*128 + i);
    __syncthreads();

    if (tid == 0) {
        float Nx=s.sX[0],Ny=s.sX[1],Nz=s.sX[2];
        float Ax=s.sX[3],Ay=s.sX[4],Az=s.sX[5];
        float Cx=s.sX[6],Cy=s.sX[7],Cz=s.sX[8];
        float v1x=Cx-Ax, v1y=Cy-Ay, v1z=Cz-Az;
        float v2x=Nx-Ax, v2y=Ny-Ay, v2z=Nz-Az;
        float r1 = 1.f/sqrtf(v1x*v1x+v1y*v1y+v1z*v1z + 1e-8f);
        float e1x=v1x*r1, e1y=v1y*r1, e1z=v1z*r1;
        float dp = e1x*v2x+e1y*v2y+e1z*v2z;
        float u2x=v2x-e1x*dp, u2y=v2y-e1y*dp, u2z=v2z-e1z*dp;
        float r2 = 1.f/sqrtf(u2x*u2x+u2y*u2y+u2z*u2z + 1e-8f);
        float e2x=u2x*r2, e2y=u2y*r2, e2z=u2z*r2;
        float e3x = e1y*e2z - e1z*e2y;
        float e3y = e1z*e2x - e1x*e2z;
        float e3z = e1x*e2y - e1y*e2x;
        s.sR[0]=e1x; s.sR[1]=e2x; s.sR[2]=e3x;
        s.sR[3]=e1y; s.sR[4]=e2y; s.sR[5]=e3y;
        s.sR[6]=e1z; s.sR[7]=e2z; s.sR[8]=e3z;
        s.st[0]=Ax*0.1f; s.st[1]=Ay*0.1f; s.st[2]=Az*0.1f;
    }
    if (tid < 24) {
        float acc = ldf<F32>(bp, tid);
        const unsigned short* wr = wpT + (long)tid*128;
        #pragma unroll
        for (int c=0;c<16;c++){
            ushort4 w0 = *reinterpret_cast<const ushort4*>(wr + c*8);
            ushort4 w1 = *reinterpret_cast<const ushort4*>(wr + c*8 + 4);
            acc += s.hvs[c*8+0]*us2f(w0.x) + s.hvs[c*8+1]*us2f(w0.y)
                 + s.hvs[c*8+2]*us2f(w0.z) + s.hvs[c*8+3]*us2f(w0.w)
                 + s.hvs[c*8+4]*us2f(w1.x) + s.hvs[c*8+5]*us2f(w1.y)
                 + s.hvs[c*8+6]*us2f(w1.z) + s.hvs[c*8+7]*us2f(w1.w);
        }
        s.spl[tid] = acc;
    }
    __syncthreads();

    if (tid < 24) {
        pl[n*24+tid] = s.spl[tid];
        int p = tid/3, c = tid - p*3;
        float g = s.sR[c*3+0]*s.spl[p*3+0] + s.sR[c*3+1]*s.spl[p*3+1]
                + s.sR[c*3+2]*s.spl[p*3+2] + s.st[c];
        pg[n*24+tid] = g;
    }
    if (tid < 9) Rw[n*9+tid] = s.sR[tid];
    if (tid < 3) tw[n*3+tid] = s.st[tid];
    if (tid < 8) {
        float a=s.spl[tid*3], b=s.spl[tid*3+1], c=s.spl[tid*3+2];
        pln[n*8+tid] = sqrtf(a*a+b*b+c*c + 1e-8f);
    }
}

__global__ __launch_bounds__(64) void prep_k(
    const void* __restrict__ hV, const void* __restrict__ X,
    const unsigned short* __restrict__ wpT, const void* __restrict__ bp,
    float* __restrict__ pg, float* __restrict__ pl, float* __restrict__ pln,
    float* __restrict__ Rw, float* __restrict__ tw, const void* __restrict__ maskV)
{
    __shared__ PrepSmem s;
    int n = blockIdx.x, tid = threadIdx.x;
    if (is_f32(maskV)) prep_body<true >(hV,X,wpT,bp,pg,pl,pln,Rw,tw,s,n,tid);
    else               prep_body<false>(hV,X,wpT,bp,pg,pl,pln,Rw,tw,s,n,tid);
}

// ---------------------------------------------------------------------------
// Kernel B1: edge-MLP. 2 nodes/block, 128 threads = 2 waves (wave = n-half).
//   Barrier-free K-loop: A-fragments loaded directly from global/geo-LDS.
//   One 17.4 KB LDS slab serves geo -> m1 -> m2 (6 barriers total).
//   Wave 0 streams hE back out as the passthrough output during chunks 4-7.
// ---------------------------------------------------------------------------
#define ASTRIDE 40    // 32 + 8 pad (80B rows, 16B-aligned)
#define MSTRIDE 136   // 128 + 8 pad (272B rows, 16B-aligned)

struct __align__(16) Mp1Smem {
    union __align__(16) {
        unsigned short geo[3][64*ASTRIDE];   // 15.4 KB, dead after layer-1
        unsigned short m[64*MSTRIDE];        // 17.4 KB slab: m1 then m2
    } u;
    int   sj[64];        // per edge-row: global neighbor node index
    float smka[64];      // per edge-row mask
    float spg[2][24], spl[2][24], spln[2][8], sR[2][9], st3[2][3];
};

template<bool F32>
DEV void mpnn1_body(
    const void* hV, const void* hE, const void* maskA,
    const void* bm1, const void* bm2, const void* bm3, const int* Eidx,
    const float* pg, const float* pl, const float* pln,
    const float* Rw, const float* tw,
    const unsigned short* wt1, const unsigned short* wt2, const unsigned short* wt3,
    float* nodemsg, void* outE, Mp1Smem& sm, int n0, int tid)
{
    const int lane = tid & 63, w = tid >> 6;     // w = n-half (0/1)
    const int lm = lane & 15, quad = lane >> 4;

    // ---- stage 0
    if (tid < 64) { int l = tid >> 5;
        sm.sj[tid] = (((n0+l) >> 9) << 9) + Eidx[(long)(n0+l)*32 + (tid & 31)];
    } else { int t = tid - 64; int l = t >> 5;
        sm.smka[t] = ldf<F32>(maskA, (long)(n0+l)*32 + (t & 31));
    }
    if (tid < 48)        { sm.spg[tid/24][tid%24] = pg[(n0+tid/24)*24 + tid%24]; }
    else if (tid < 96)   { int t=tid-48; sm.spl[t/24][t%24] = pl[(n0+t/24)*24 + t%24]; }
    else if (tid < 112)  { int t=tid-96; sm.spln[t>>3][t&7]  = pln[(n0+(t>>3))*8 + (t&7)]; }
    if (tid < 18)        { sm.sR[tid/9][tid%9] = Rw[(n0+tid/9)*9 + tid%9]; }
    else if (tid < 24)   { int t=tid-18; sm.st3[t/3][t%3] = tw[(n0+t/3)*3 + t%3]; }
    __syncthreads();                                   // bar0

    // ---- geo chunks (k=384..479), 512 (row,p) tasks over 128 threads
    #pragma unroll
    for (int pass=0; pass<4; ++pass) {
        int v = tid + pass*128;
        int row = v >> 3, p = v & 7, nd = row >> 5;
        int j = sm.sj[row];
        float qx = pg[j*24 + p*3 + 0];
        float qy = pg[j*24 + p*3 + 1];
        float qz = pg[j*24 + p*3 + 2];
        float dx = sm.spg[nd][p*3+0]-qx, dy = sm.spg[nd][p*3+1]-qy, dz = sm.spg[nd][p*3+2]-qz;
        float npg = sqrtf(dx*dx+dy*dy+dz*dz + 1e-8f);
        float ux = qx - sm.st3[nd][0], uy = qy - sm.st3[nd][1], uz = qz - sm.st3[nd][2];
        float l0 = sm.sR[nd][0]*ux + sm.sR[nd][3]*uy + sm.sR[nd][6]*uz;
        float l1 = sm.sR[nd][1]*ux + sm.sR[nd][4]*uy + sm.sR[nd][7]*uz;
        float l2v= sm.sR[nd][2]*ux + sm.sR[nd][5]*uy + sm.sR[nd][8]*uz;
        float npl = sqrtf(l0*l0+l1*l1+l2v*l2v + 1e-8f);
        unsigned short* C0 = sm.u.geo[0];
        unsigned short* C1 = sm.u.geo[1];
        unsigned short* C2 = sm.u.geo[2];
        C0[row*ASTRIDE + p*3+0] = f2us(sm.spl[nd][p*3+0]);
        C0[row*ASTRIDE + p*3+1] = f2us(sm.spl[nd][p*3+1]);
        C0[row*ASTRIDE + p*3+2] = f2us(sm.spl[nd][p*3+2]);
        C0[row*ASTRIDE + 24+p]  = f2us(sm.spln[nd][p]);
        C1[row*ASTRIDE + p*3+0] = f2us(l0);
        C1[row*ASTRIDE + p*3+1] = f2us(l1);
        C1[row*ASTRIDE + p*3+2] = f2us(l2v);
        C1[row*ASTRIDE + 24+p]  = f2us(npl);
        C2[row*ASTRIDE + p]     = f2us(npg);
    }
    for (int z = tid; z < 64*24; z += 128) {
        int row = z / 24, col = 8 + (z % 24);
        sm.u.geo[2][row*ASTRIDE + col] = 0;
    }
    __syncthreads();                                   // bar1

    int sjv[4];
    #pragma unroll
    for (int mt=0; mt<4; ++mt) sjv[mt] = sm.sj[16*mt + lm];

    const unsigned short* wr1[4];
    #pragma unroll
    for (int nt=0; nt<4; ++nt) wr1[nt] = wt1 + (long)(64*w + nt*16 + lm)*480 + quad*8;

    f32x4 acc[4][4];
    #pragma unroll
    for (int nt=0; nt<4; ++nt) {
        float b0 = ldf<F32>(bm1, 64*w + nt*16 + lm);
        f32x4 iv = {b0,b0,b0,b0};
        #pragma unroll
        for (int mt=0; mt<4; ++mt) acc[mt][nt] = iv;
    }

    // ---- layer 1: barrier-free K-loop (15 chunks of 32)
    for (int c=0; c<15; ++c) {
        s16x8 av[4];
        if (c < 12) {
            #pragma unroll
            for (int mt=0; mt<4; ++mt) {
                int row16 = 16*mt + lm, nd = mt >> 1;
                const void* base; long src;
                if (c < 4)      { base = hV; src = (long)(n0+nd)*128 + c*32 + quad*8; }
                else if (c < 8) { base = hE; src = ((long)(n0+nd)*32 + (row16&31))*128 + (c-4)*32 + quad*8; }
                else            { base = hV; src = (long)sjv[mt]*128 + (c-8)*32 + quad*8; }
                U16x8 pk;
                if (F32) {
                    const float4* vp = reinterpret_cast<const float4*>(reinterpret_cast<const float*>(base) + src);
                    float4 x = vp[0], y = vp[1];
                    if (c >= 4 && c < 8 && w == 0) {
                        float4* d = reinterpret_cast<float4*>(reinterpret_cast<float*>(outE) + src);
                        d[0] = x; d[1] = y;
                    }
                    pk.u.x = pack2(x.x,x.y); pk.u.y = pack2(x.z,x.w);
                    pk.u.z = pack2(y.x,y.y); pk.u.w = pack2(y.z,y.w);
                } else {
                    pk.u = *reinterpret_cast<const uint4*>(reinterpret_cast<const unsigned short*>(base) + src);
                    if (c >= 4 && c < 8 && w == 0)
                        *reinterpret_cast<uint4*>(reinterpret_cast<unsigned short*>(outE) + src) = pk.u;
                }
                av[mt] = pk.v;
            }
        } else {
            #pragma unroll
            for (int mt=0; mt<4; ++mt)
                av[mt] = *reinterpret_cast<const s16x8*>(&sm.u.geo[c-12][(16*mt+lm)*ASTRIDE + quad*8]);
        }
        #pragma unroll
        for (int nt=0; nt<4; ++nt) {
            s16x8 bf = *reinterpret_cast<const s16x8*>(wr1[nt] + (long)c*32);
            #pragma unroll
            for (int mt=0; mt<4; ++mt)
                acc[mt][nt] = __builtin_amdgcn_mfma_f32_16x16x32_bf16(av[mt], bf, acc[mt][nt], 0,0,0);
        }
    }
    __syncthreads();                                   // bar2 (geo dead; one store/load drain)

    // ---- m1 write (relu)
    #pragma unroll
    for (int mt=0; mt<4; ++mt)
        #pragma unroll
        for (int nt=0; nt<4; ++nt)
            #pragma unroll
            for (int r=0; r<4; ++r)
                sm.u.m[(16*mt + quad*4 + r)*MSTRIDE + 64*w + nt*16 + lm]
                    = f2us(fmaxf(acc[mt][nt][r], 0.f));
    __syncthreads();                                   // bar3 (m1 ready)

    // ---- layer 2
    #pragma unroll
    for (int nt=0; nt<4; ++nt) {
        float b0 = ldf<F32>(bm2, 64*w + nt*16 + lm);
        f32x4 iv = {b0,b0,b0,b0};
        #pragma unroll
        for (int mt=0; mt<4; ++mt) acc[mt][nt] = iv;
    }
    #pragma unroll
    for (int kc=0; kc<4; ++kc) {
        s16x8 av[4];
        #pragma unroll
        for (int mt=0; mt<4; ++mt)
            av[mt] = *reinterpret_cast<const s16x8*>(&sm.u.m[(16*mt+lm)*MSTRIDE + kc*32 + quad*8]);
        #pragma unroll
        for (int nt=0; nt<4; ++nt) {
            s16x8 bf = *reinterpret_cast<const s16x8*>(&wt2[(long)(64*w + nt*16 + lm)*128 + kc*32 + quad*8]);
            #pragma unroll
            for (int mt=0; mt<4; ++mt)
                acc[mt][nt] = __builtin_amdgcn_mfma_f32_16x16x32_bf16(av[mt], bf, acc[mt][nt], 0,0,0);
        }
    }
    __syncthreads();                                   // bar4 (m1 reads done)

    #pragma unroll
    for (int mt=0; mt<4; ++mt)
        #pragma unroll
        for (int nt=0; nt<4; ++nt)
            #pragma unroll
            for (int r=0; r<4; ++r)
                sm.u.m[(16*mt + quad*4 + r)*MSTRIDE + 64*w + nt*16 + lm]
                    = f2us(fmaxf(acc[mt][nt][r], 0.f));
    __syncthreads();                                   // bar5 (m2 ready)

    // ---- layer 3
    #pragma unroll
    for (int nt=0; nt<4; ++nt) {
        float b0 = ldf<F32>(bm3, 64*w + nt*16 + lm);
        f32x4 iv = {b0,b0,b0,b0};
        #pragma unroll
        for (int mt=0; mt<4; ++mt) acc[mt][nt] = iv;
    }
    #pragma unroll
    for (int kc=0; kc<4; ++kc) {
        s16x8 av[4];
        #pragma unroll
        for (int mt=0; mt<4; ++mt)
            av[mt] = *reinterpret_cast<const s16x8*>(&sm.u.m[(16*mt+lm)*MSTRIDE + kc*32 + quad*8]);
        #pragma unroll
        for (int nt=0; nt<4; ++nt) {
            s16x8 bf = *reinterpret_cast<const s16x8*>(&wt3[(long)(64*w + nt*16 + lm)*128 + kc*32 + quad*8]);
            #pragma unroll
            for (int mt=0; mt<4; ++mt)
                acc[mt][nt] = __builtin_amdgcn_mfma_f32_16x16x32_bf16(av[mt], bf, acc[mt][nt], 0,0,0);
        }
    }

    // ---- masked sum over each node's 32 edges (no barrier needed)
    #pragma unroll
    for (int nt=0; nt<4; ++nt) {
        float s0 = 0.f, s1 = 0.f;
        #pragma unroll
        for (int r=0; r<4; ++r) {
            s0 += acc[0][nt][r] * sm.smka[     quad*4 + r]
                + acc[1][nt][r] * sm.smka[16 + quad*4 + r];
            s1 += acc[2][nt][r] * sm.smka[32 + quad*4 + r]
                + acc[3][nt][r] * sm.smka[48 + quad*4 + r];
        }
        s0 += __shfl_xor(s0, 16); s0 += __shfl_xor(s0, 32);
        s1 += __shfl_xor(s1, 16); s1 += __shfl_xor(s1, 32);
        if (lane < 16) {
            nodemsg[(long)(n0  )*128 + 64*w + nt*16 + lane] = s0;
            nodemsg[(long)(n0+1)*128 + 64*w + nt*16 + lane] = s1;
        }
    }
}

__global__ __launch_bounds__(128) void mpnn1_k(
    const void* __restrict__ hV, const void* __restrict__ hE,
    const void* __restrict__ maskV, const void* __restrict__ maskA,
    const void* __restrict__ bm1, const void* __restrict__ bm2, const void* __restrict__ bm3,
    const int* __restrict__ Eidx,
    const float* __restrict__ pg, const float* __restrict__ pl,
    const float* __restrict__ pln, const float* __restrict__ Rw,
    const float* __restrict__ tw,
    const unsigned short* __restrict__ wt1, const unsigned short* __restrict__ wt2,
    const unsigned short* __restrict__ wt3,
    float* __restrict__ nodemsg, void* __restrict__ dout)
{
    __shared__ Mp1Smem sm;
    int n0 = blockIdx.x * 2, tid = threadIdx.x;
    if (is_f32(maskV)) {
        void* outE = reinterpret_cast<float*>(dout) + 524288;
        mpnn1_body<true >(hV,hE,maskA,bm1,bm2,bm3,Eidx,pg,pl,pln,Rw,tw,wt1,wt2,wt3,nodemsg,outE,sm,n0,tid);
    } else {
        void* outE = reinterpret_cast<unsigned short*>(dout) + 524288;
        mpnn1_body<false>(hV,hE,maskA,bm1,bm2,bm3,Eidx,pg,pl,pln,Rw,tw,wt1,wt2,wt3,nodemsg,outE,sm,n0,tid);
    }
}

// ---------------------------------------------------------------------------
// Kernel B2: node FFN. 32 nodes/block, 128 blocks, 256 threads = 4 waves.
//   wave w: m-tile mt=w>>1 (16 rows), n-half h=w&1.
// ---------------------------------------------------------------------------
#define TSTRIDE 520   // 512 + 8 pad

struct __align__(16) FfnSmem {
    unsigned short x1[32*MSTRIDE];                    // 8.7 KB (LN1 out, bf16)
    union __align__(16) {
        unsigned short t1[32*TSTRIDE];                // 33.3 KB hidden (bf16)
        float yf[32*132];                             // 16.9 KB pre-LN2 (fp32)
    } u;
};

template<bool F32>
DEV void ffn_body(const void* hV, const void* maskV, const float* nodemsg,
                  const void* g1, const void* be1, const void* bd1, const void* bd2,
                  const void* g2, const void* be2,
                  const unsigned short* wd1T, const unsigned short* wd2T,
                  void* out, FfnSmem& sm, int n0, int tid)
{
    const int lane = tid & 63, w = tid >> 6;
    const int mt = w >> 1, h = w & 1;
    const int lm = lane & 15, quad = lane >> 4;

    // ---- x = hV + nodemsg/32 ; LN1 -> x1 (bf16). thread: row r, 16 cols.
    {
        const int r = tid >> 3, c0 = (tid & 7) * 16;
        const long nb = (long)(n0 + r)*128;
        float xv[16];
        float s1 = 0.f, s2 = 0.f;
        #pragma unroll
        for (int j=0; j<16; ++j) {
            float v = ldf<F32>(hV, nb + c0 + j) + nodemsg[nb + c0 + j] * (1.f/32.f);
            xv[j] = v; s1 += v; s2 += v*v;
        }
        s1 += __shfl_xor(s1,1); s1 += __shfl_xor(s1,2); s1 += __shfl_xor(s1,4);
        s2 += __shfl_xor(s2,1); s2 += __shfl_xor(s2,2); s2 += __shfl_xor(s2,4);
        float mu = s1 * (1.f/128.f);
        float var = s2 * (1.f/128.f) - mu*mu;
        float rs = 1.f/sqrtf(var + 1e-5f);
        #pragma unroll
        for (int j=0; j<16; ++j) {
            int c = c0 + j;
            sm.x1[r*MSTRIDE + c] = f2us((xv[j]-mu)*rs*ldf<F32>(g1, c) + ldf<F32>(be1, c));
        }
    }
    __syncthreads();

    // ---- d1: 128 -> 512 (wave: 16 rows x 256 cols), relu -> t1
    {
        f32x4 t1a[16];
        #pragma unroll
        for (int nt=0; nt<16; ++nt) {
            float b0 = ldf<F32>(bd1, 256*h + nt*16 + lm);
            f32x4 iv = {b0,b0,b0,b0};
            t1a[nt] = iv;
        }
        #pragma unroll
        for (int kc=0; kc<4; ++kc) {
            s16x8 a = *reinterpret_cast<const s16x8*>(&sm.x1[(16*mt+lm)*MSTRIDE + kc*32 + quad*8]);
            #pragma unroll
            for (int nt=0; nt<16; ++nt) {
                s16x8 bf = *reinterpret_cast<const s16x8*>(&wd1T[(long)(256*h + nt*16 + lm)*128 + kc*32 + quad*8]);
                t1a[nt] = __builtin_amdgcn_mfma_f32_16x16x32_bf16(a, bf, t1a[nt], 0,0,0);
            }
        }
        #pragma unroll
        for (int nt=0; nt<16; ++nt)
            #pragma unroll
            for (int r=0; r<4; ++r)
                sm.u.t1[(16*mt + quad*4 + r)*TSTRIDE + 256*h + nt*16 + lm] = f2us(fmaxf(t1a[nt][r], 0.f));
    }
    __syncthreads();

    // ---- d2: 512 -> 128 (wave: 16 rows x 64 cols)
    f32x4 yacc[4];
    #pragma unroll
    for (int nt=0; nt<4; ++nt) {
        float b0 = ldf<F32>(bd2, 64*h + nt*16 + lm);
        f32x4 iv = {b0,b0,b0,b0};
        yacc[nt] = iv;
    }
    #pragma unroll
    for (int kc=0; kc<16; ++kc) {
        s16x8 a = *reinterpret_cast<const s16x8*>(&sm.u.t1[(16*mt+lm)*TSTRIDE + kc*32 + quad*8]);
        #pragma unroll
        for (int nt=0; nt<4; ++nt) {
            s16x8 bf = *reinterpret_cast<const s16x8*>(&wd2T[(long)(64*h + nt*16 + lm)*512 + kc*32 + quad*8]);
            yacc[nt] = __builtin_amdgcn_mfma_f32_16x16x32_bf16(a, bf, yacc[nt], 0,0,0);
        }
    }
    __syncthreads();   // t1 reads done before yf (alias) writes

    #pragma unroll
    for (int nt=0; nt<4; ++nt)
        #pragma unroll
        for (int r=0; r<4; ++r) {
            int rr = 16*mt + quad*4 + r, c = 64*h + nt*16 + lm;
            sm.u.yf[rr*132 + c] = yacc[nt][r] + us2f(sm.x1[rr*MSTRIDE + c]);
        }
    __syncthreads();

    // ---- LN2 + mask + store
    {
        const int r = tid >> 3, c0 = (tid & 7) * 16;
        float yv[16];
        float s1 = 0.f, s2 = 0.f;
        #pragma unroll
        for (int j=0; j<16; ++j) {
            float v = sm.u.yf[r*132 + c0 + j];
            yv[j] = v; s1 += v; s2 += v*v;
        }
        s1 += __shfl_xor(s1,1); s1 += __shfl_xor(s1,2); s1 += __shfl_xor(s1,4);
        s2 += __shfl_xor(s2,1); s2 += __shfl_xor(s2,2); s2 += __shfl_xor(s2,4);
        float mu = s1 * (1.f/128.f);
        float var = s2 * (1.f/128.f) - mu*mu;
        float rs = 1.f/sqrtf(var + 1e-5f);
        float mv = ldf<F32>(maskV, n0 + r);
        const long ob = (long)(n0 + r)*128 + c0;
        #pragma unroll
        for (int j=0; j<16; ++j) {
            int c = c0 + j;
            float v = ((yv[j]-mu)*rs*ldf<F32>(g2, c) + ldf<F32>(be2, c)) * mv;
            if (F32) reinterpret_cast<float*>(out)[ob + j] = v;
            else     reinterpret_cast<unsigned short*>(out)[ob + j] = f2us(v);
        }
    }
}

__global__ __launch_bounds__(256) void ffn_k(
    const void* __restrict__ hV, const void* __restrict__ maskV,
    const float* __restrict__ nodemsg,
    const void* __restrict__ g1, const void* __restrict__ be1,
    const void* __restrict__ bd1, const void* __restrict__ bd2,
    const void* __restrict__ g2, const void* __restrict__ be2,
    const unsigned short* __restrict__ wd1T, const unsigned short* __restrict__ wd2T,
    void* __restrict__ out)
{
    __shared__ FfnSmem sm;
    int n0 = blockIdx.x * 32, tid = threadIdx.x;
    if (is_f32(maskV))
        ffn_body<true >(hV,maskV,nodemsg,g1,be1,bd1,bd2,g2,be2,wd1T,wd2T,out,sm,n0,tid);
    else
        ffn_body<false>(hV,maskV,nodemsg,g1,be1,bd1,bd2,g2,be2,wd1T,wd2T,out,sm,n0,tid);
}

// ---------------------------------------------------------------------------
extern "C" void kernel_launch(void* const* d_in, const int* in_sizes, int n_in,
                              void* d_out, int out_size, void* d_ws, size_t ws_size,
                              hipStream_t stream)
{
    const void* hV    = d_in[0];
    const void* hE    = d_in[1];
    const void* X     = d_in[2];
    const void* maskV = d_in[3];
    const void* maskA = d_in[4];
    const void* Wp    = d_in[5];
    const void* bp    = d_in[6];
    const void* Wm1   = d_in[7];
    const void* bm1   = d_in[8];
    const void* Wm2   = d_in[9];
    const void* bm2   = d_in[10];
    const void* Wm3   = d_in[11];
    const void* bm3   = d_in[12];
    const void* g1    = d_in[13];
    const void* be1   = d_in[14];
    const void* Wd1   = d_in[15];
    const void* bd1   = d_in[16];
    const void* Wd2   = d_in[17];
    const void* bd2   = d_in[18];
    const void* g2    = d_in[19];
    const void* be2   = d_in[20];
    const int*  Eidx  = (const int*)d_in[21];

    float* ws = (float*)d_ws;
    float* pg  = ws;                 // 98304
    float* pl  = ws + 98304;         // 98304
    float* pln = ws + 196608;        // 32768
    float* Rw  = ws + 229376;        // 36864
    float* tw  = ws + 266240;        // 12288
    float* nm  = ws + 278528;        // 524288
    unsigned short* wt1  = (unsigned short*)(ws + 802816);  // 61440
    unsigned short* wt2  = wt1 + 61440;                     // 16384
    unsigned short* wt3  = wt2 + 16384;                     // 16384
    unsigned short* wpT  = wt3 + 16384;                     // 3072
    unsigned short* wd1T = wpT + 3072;                      // 65536
    unsigned short* wd2T = wd1T + 65536;                    // 65536

    wtrans_k<<<892, 256, 0, stream>>>(Wm1, Wm2, Wm3, Wp, Wd1, Wd2,
                                      wt1, wt2, wt3, wpT, wd1T, wd2T, maskV);

    prep_k<<<4096, 64, 0, stream>>>(hV, X, wpT, bp, pg, pl, pln, Rw, tw, maskV);

    mpnn1_k<<<2048, 128, 0, stream>>>(hV, hE, maskV, maskA, bm1, bm2, bm3, Eidx,
                                      pg, pl, pln, Rw, tw, wt1, wt2, wt3,
                                      nm, d_out);

    ffn_k<<<128, 256, 0, stream>>>(hV, maskV, nm, g1, be1, bd1, bd2, g2, be2,
                                   wd1T, wd2T, d_out);
}